// Round 1
// baseline (164.531 us; speedup 1.0000x reference)
//
#include <hip/hip_runtime.h>

// Problem constants (AttentionMechanismVaswani): B=2, G=2048, D=128, H=8, K=V=16
constexpr int Bc = 2, Gc = 2048, Dc = 128, Hc = 8, Kc = 16;

typedef __attribute__((ext_vector_type(8))) short bf16x8;
typedef __attribute__((ext_vector_type(4))) unsigned short u16x4;
typedef __attribute__((ext_vector_type(4))) float f32x4;

// f32 -> bf16 round-to-nearest-even, as raw bits
static __device__ __forceinline__ unsigned short f2bf(float f) {
  unsigned int u = __float_as_uint(f);
  u += 0x7FFFu + ((u >> 16) & 1u);
  return (unsigned short)(u >> 16);
}
static __device__ __forceinline__ float bf2f(unsigned short s) {
  return __uint_as_float(((unsigned int)s) << 16);
}

// ---------------------------------------------------------------------------
// Kernel 1: projections. Computes per (b,h,g):
//   Q[bh][g][16]  f32, pre-scaled by compat_factor = 0.25
//   Khi/Klo[bh][g][16]   bf16 split of K
//   VhiT/VloT[bh][v][g]  bf16 split of V, transposed for the PV A-operand
// Grid: B * G/4 blocks of 384 threads; each block owns 4 h-rows.
//   tid 0..127  : Q  (gl = tid/32, h = (tid/4)%8, 4 cols)
//   tid 128..255: K  (same mapping)
//   tid 256..383: V  (h = t/16, vcol = t%16, all 4 g-rows -> transposed store)
// ---------------------------------------------------------------------------
__global__ __launch_bounds__(384) void proj_kernel(
    const float* __restrict__ h, const float* __restrict__ Wq,
    const float* __restrict__ Wk, const float* __restrict__ Wv,
    float* __restrict__ Q, unsigned short* __restrict__ Khi,
    unsigned short* __restrict__ Klo, unsigned short* __restrict__ VhiT,
    unsigned short* __restrict__ VloT) {
  __shared__ float hrow[4][132];  // +4 pad breaks 4-way bank conflict for V threads
  const int b = blockIdx.x >> 9;     // / 512
  const int gc = blockIdx.x & 511;
  const int tid = threadIdx.x;
  for (int idx = tid; idx < 4 * Dc; idx += 384) {
    hrow[idx >> 7][idx & 127] =
        h[((size_t)b * Gc + (gc * 4 + (idx >> 7))) * Dc + (idx & 127)];
  }
  __syncthreads();

  if (tid < 256) {
    const int mat = tid >> 7;          // 0 = Q, 1 = K
    const int t = tid & 127;
    const int gl = t >> 5;             // g-row 0..3
    const int hh = (t >> 2) & 7;       // head
    const int c0 = (t & 3) << 2;       // col group *4
    const float* W = (mat == 0 ? Wq : Wk) + hh * (Dc * Kc) + c0;
    float a0 = 0.f, a1 = 0.f, a2 = 0.f, a3 = 0.f;
#pragma unroll 4
    for (int d = 0; d < Dc; ++d) {
      const float hv = hrow[gl][d];
      const float4 w = *(const float4*)(W + d * Kc);
      a0 += hv * w.x; a1 += hv * w.y; a2 += hv * w.z; a3 += hv * w.w;
    }
    const int g = gc * 4 + gl;
    const size_t off = ((size_t)(b * Hc + hh) * Gc + g) * Kc + c0;
    if (mat == 0) {
      float4 o;
      o.x = a0 * 0.25f; o.y = a1 * 0.25f; o.z = a2 * 0.25f; o.w = a3 * 0.25f;
      *(float4*)(Q + off) = o;
    } else {
      float a[4] = {a0, a1, a2, a3};
      u16x4 hi, lo;
#pragma unroll
      for (int i = 0; i < 4; ++i) {
        const unsigned short hb = f2bf(a[i]);
        hi[i] = hb;
        lo[i] = f2bf(a[i] - bf2f(hb));  // exact residual (Sterbenz)
      }
      *(u16x4*)(Khi + off) = hi;
      *(u16x4*)(Klo + off) = lo;
    }
  } else {
    const int t = tid - 256;
    const int hh = t >> 4;
    const int vc = t & 15;
    const float* W = Wv + hh * (Dc * Kc) + vc;
    float a0 = 0.f, a1 = 0.f, a2 = 0.f, a3 = 0.f;
#pragma unroll 4
    for (int d = 0; d < Dc; ++d) {
      const float w = W[d * Kc];
      a0 += hrow[0][d] * w; a1 += hrow[1][d] * w;
      a2 += hrow[2][d] * w; a3 += hrow[3][d] * w;
    }
    const int g0 = gc * 4;
    const size_t off = ((size_t)(b * Hc + hh) * Kc + vc) * Gc + g0;
    float a[4] = {a0, a1, a2, a3};
    u16x4 hi, lo;
#pragma unroll
    for (int i = 0; i < 4; ++i) {
      const unsigned short hb = f2bf(a[i]);
      hi[i] = hb;
      lo[i] = f2bf(a[i] - bf2f(hb));
    }
    *(u16x4*)(VhiT + off) = hi;   // 4 consecutive g -> coalesced 8B store
    *(u16x4*)(VloT + off) = lo;
  }
}

// ---------------------------------------------------------------------------
// Kernel 2: flash attention. One wave per (b,h, 16-row q-tile).
// S^T = mfma(K, Q): A = K-chunk [m=16][kdim=32 = 16d x {hi,lo}],
//                   B = Q^T    [kdim=32][q=16]  (bql then bqh, chained C)
// Score C-layout [m=(l>>4)*4+i][q=l&15] feeds PV's B-operand directly.
// PV: o^T += mfma(A={vh,vh}, B={ph,pl}) + mfma(A={vl,vl}, B={ph,pl})
//   -> full (ph+pl)*(vh+vl) = p*v to ~2^-18 relative.
// ---------------------------------------------------------------------------
__global__ __launch_bounds__(64) void flash_kernel(
    const float* __restrict__ Q, const unsigned short* __restrict__ Khi,
    const unsigned short* __restrict__ Klo,
    const unsigned short* __restrict__ VhiT,
    const unsigned short* __restrict__ VloT, float* __restrict__ out) {
  const int bh = blockIdx.x >> 7;    // / 128
  const int qi = blockIdx.x & 127;   // q-tile within (b,h)
  const int l = threadIdx.x;         // lane 0..63
  const int lane15 = l & 15;         // q for B/D cols; m for K rows; v for V rows
  const int g4 = l >> 4;             // lane group 0..3
  const int dhalf = g4 & 1;          // which 8 dims of the 16-d head

  // Q fragments (B-operand), loop-invariant. Groups {0,1}: d 0-7 / 8-15 (hi&lo
  // built from same f32 row; part selection is on the K side via lane group).
  const float* qp = Q + ((size_t)bh * Gc + qi * 16 + lane15) * Kc + 8 * dhalf;
  bf16x8 bqh, bql;
#pragma unroll
  for (int i = 0; i < 8; ++i) {
    const float x = qp[i];
    const unsigned short hb = f2bf(x);
    bqh[i] = (short)hb;
    bql[i] = (short)f2bf(x - bf2f(hb));
  }

  // K A-fragment base: groups 0,1 read Khi; groups 2,3 read Klo (k-slots 16-31)
  const unsigned short* kbase = (g4 >= 2 ? Klo : Khi) +
      (size_t)bh * Gc * Kc + lane15 * Kc + 8 * dhalf;
  const unsigned short* vhbase = VhiT + ((size_t)bh * Kc + lane15) * Gc + 4 * g4;
  const unsigned short* vlbase = VloT + ((size_t)bh * Kc + lane15) * Gc + 4 * g4;

  f32x4 o = {0.f, 0.f, 0.f, 0.f};
  float run_max = -1e30f, run_sum = 0.f;

  for (int c = 0; c < Gc / 16; ++c) {
    const bf16x8 ak = *(const bf16x8*)(kbase + c * 256);  // 16 rows x 16 shorts
    f32x4 s = {0.f, 0.f, 0.f, 0.f};
    s = __builtin_amdgcn_mfma_f32_16x16x32_bf16(ak, bql, s, 0, 0, 0);
    s = __builtin_amdgcn_mfma_f32_16x16x32_bf16(ak, bqh, s, 0, 0, 0);
    // s[i] = S^T[m = c*16 + 4*g4 + i][q = lane15], already scaled by 0.25 via Q

    // online softmax (per q-row = per lane15; state replicated across groups)
    float cm = fmaxf(fmaxf(s[0], s[1]), fmaxf(s[2], s[3]));
    cm = fmaxf(cm, __shfl_xor(cm, 16));
    cm = fmaxf(cm, __shfl_xor(cm, 32));
    const float nm = fmaxf(run_max, cm);
    const float corr = __expf(run_max - nm);  // first iter: exp(-huge) = 0
    const float p0 = __expf(s[0] - nm);
    const float p1 = __expf(s[1] - nm);
    const float p2 = __expf(s[2] - nm);
    const float p3 = __expf(s[3] - nm);
    float cs = (p0 + p1) + (p2 + p3);
    cs += __shfl_xor(cs, 16);
    cs += __shfl_xor(cs, 32);
    run_sum = run_sum * corr + cs;
    run_max = nm;
    o[0] *= corr; o[1] *= corr; o[2] *= corr; o[3] *= corr;

    // P fragment: slots 0-3 = bf16(p), slots 4-7 = residual
    bf16x8 bp;
    const unsigned short h0 = f2bf(p0), h1 = f2bf(p1);
    const unsigned short h2 = f2bf(p2), h3 = f2bf(p3);
    bp[0] = (short)h0; bp[1] = (short)h1; bp[2] = (short)h2; bp[3] = (short)h3;
    bp[4] = (short)f2bf(p0 - bf2f(h0));
    bp[5] = (short)f2bf(p1 - bf2f(h1));
    bp[6] = (short)f2bf(p2 - bf2f(h2));
    bp[7] = (short)f2bf(p3 - bf2f(h3));

    // V A-fragments: lane holds V^T[v = lane15][m = c*16 + 4*g4 + i]
    const u16x4 vh = *(const u16x4*)(vhbase + c * 16);
    const u16x4 vl = *(const u16x4*)(vlbase + c * 16);
    bf16x8 a1, a2;
#pragma unroll
    for (int i = 0; i < 4; ++i) {
      a1[i] = (short)vh[i]; a1[i + 4] = (short)vh[i];
      a2[i] = (short)vl[i]; a2[i + 4] = (short)vl[i];
    }
    o = __builtin_amdgcn_mfma_f32_16x16x32_bf16(a1, bp, o, 0, 0, 0);
    o = __builtin_amdgcn_mfma_f32_16x16x32_bf16(a2, bp, o, 0, 0, 0);
  }

  const float inv = 1.0f / run_sum;
  f32x4 res;
  res[0] = o[0] * inv; res[1] = o[1] * inv;
  res[2] = o[2] * inv; res[3] = o[3] * inv;
  // o^T C-layout: lane holds v = 4*g4 + i (contiguous), q = lane15
  *(f32x4*)(out + ((size_t)bh * Gc + qi * 16 + lane15) * Kc + 4 * g4) = res;
}

extern "C" void kernel_launch(void* const* d_in, const int* in_sizes, int n_in,
                              void* d_out, int out_size, void* d_ws, size_t ws_size,
                              hipStream_t stream) {
  const float* h  = (const float*)d_in[0];
  const float* Wq = (const float*)d_in[1];
  const float* Wk = (const float*)d_in[2];
  const float* Wv = (const float*)d_in[3];
  float* out = (float*)d_out;

  const size_t NE = (size_t)Bc * Hc * Gc * Kc;  // 524288 elements per array
  float* Q             = (float*)d_ws;          // 2 MB
  unsigned short* Khi  = (unsigned short*)(Q + NE);   // 1 MB each
  unsigned short* Klo  = Khi + NE;
  unsigned short* VhiT = Klo + NE;
  unsigned short* VloT = VhiT + NE;              // total ws use: 6 MB

  proj_kernel<<<dim3(Bc * (Gc / 4)), dim3(384), 0, stream>>>(
      h, Wq, Wk, Wv, Q, Khi, Klo, VhiT, VloT);
  flash_kernel<<<dim3(Bc * Hc * (Gc / 16)), dim3(64), 0, stream>>>(
      Q, Khi, Klo, VhiT, VloT, out);
}

// Round 2
// 120.866 us; speedup vs baseline: 1.3613x; 1.3613x over previous
//
#include <hip/hip_runtime.h>

// AttentionMechanismVaswani: B=2, G=2048, D=128, H=8, K=V=16
constexpr int Gc = 2048, Dc = 128, Hc = 8, Kc = 16;
constexpr int BH = 16;        // B*H
constexpr int NROW = 4096;    // B*G
constexpr int NCT = 24;       // col-tiles of the fused projection GEMM (8Q,8K,8V)
constexpr int NCH = 128;      // G/16 kv-chunks
constexpr int SPLIT = 4;      // kv-split factor
constexpr int CPS = NCH / SPLIT;

typedef __attribute__((ext_vector_type(8))) short bf16x8;
typedef __attribute__((ext_vector_type(4))) unsigned short u16x4;
typedef __attribute__((ext_vector_type(8))) unsigned short u16x8;
typedef __attribute__((ext_vector_type(4))) float f32x4;

// f32 -> bf16 (RNE) raw bits; hi/lo split gives ~2^-17 relative precision.
static __device__ __forceinline__ unsigned short f2bf(float f) {
  unsigned int u = __float_as_uint(f);
  u += 0x7FFFu + ((u >> 16) & 1u);
  return (unsigned short)(u >> 16);
}
static __device__ __forceinline__ float bf2f(unsigned short s) {
  return __uint_as_float(((unsigned int)s) << 16);
}

// ---------------------------------------------------------------------------
// Split h [4096][128] f32 into bf16 hi/lo arrays (A-operand source).
// ---------------------------------------------------------------------------
__global__ __launch_bounds__(256) void hsplit_kernel(
    const float* __restrict__ h, unsigned short* __restrict__ hhi,
    unsigned short* __restrict__ hlo) {
  const int t = blockIdx.x * 256 + threadIdx.x;  // 131072 threads, 4 elems each
  const float4 v = *(const float4*)(h + (size_t)t * 4);
  const float a[4] = {v.x, v.y, v.z, v.w};
  u16x4 hi, lo;
#pragma unroll
  for (int i = 0; i < 4; ++i) {
    const unsigned short hb = f2bf(a[i]);
    hi[i] = hb;
    lo[i] = f2bf(a[i] - bf2f(hb));
  }
  *(u16x4*)(hhi + (size_t)t * 4) = hi;
  *(u16x4*)(hlo + (size_t)t * 4) = lo;
}

// ---------------------------------------------------------------------------
// Pack W (Q pre-scaled by 0.25) into MFMA B-fragment layout, hi/lo split:
// Wf[ct][kc][lane][8] where ct = mat*8+head, k-slot 8*(l>>4)+j -> d, col l&15.
// ---------------------------------------------------------------------------
__global__ __launch_bounds__(256) void wsplit_kernel(
    const float* __restrict__ Wq, const float* __restrict__ Wk,
    const float* __restrict__ Wv, unsigned short* __restrict__ WfH,
    unsigned short* __restrict__ WfL) {
  const int t = blockIdx.x * 256 + threadIdx.x;  // 6144 threads: (ct,kc,l)
  const int l = t & 63;
  const int kc = (t >> 6) & 3;
  const int ct = t >> 8;
  const int mat = ct >> 3, hh = ct & 7;
  const float* W = (mat == 0 ? Wq : (mat == 1 ? Wk : Wv)) + hh * (Dc * Kc);
  const float scale = (mat == 0) ? 0.25f : 1.0f;  // fold compat_factor into W_Q
  const int col = l & 15, g4 = l >> 4;
  u16x8 hi, lo;
#pragma unroll
  for (int j = 0; j < 8; ++j) {
    const int d = kc * 32 + g4 * 8 + j;
    const float w = W[d * Kc + col] * scale;
    const unsigned short hb = f2bf(w);
    hi[j] = hb;
    lo[j] = f2bf(w - bf2f(hb));
  }
  *(u16x8*)(WfH + (size_t)t * 8) = hi;
  *(u16x8*)(WfL + (size_t)t * 8) = lo;
}

// ---------------------------------------------------------------------------
// Fused projection GEMM: C[4096, 384] = h * [0.25*Wq | Wk | Wv] via
// split-bf16 (hh*wh + hh*wl + hl*wh; lo*lo dropped, ~2^-18).
// One wave per 16x16 tile; 4 waves/block share the A row-tile.
// Epilogues: Q -> f32; K -> hi/lo bf16 row-major; V -> duplicated PV A-frag.
// ---------------------------------------------------------------------------
__global__ __launch_bounds__(256) void proj_gemm_kernel(
    const unsigned short* __restrict__ hhi, const unsigned short* __restrict__ hlo,
    const unsigned short* __restrict__ WfH, const unsigned short* __restrict__ WfL,
    float* __restrict__ Q, unsigned short* __restrict__ Khi,
    unsigned short* __restrict__ Klo, unsigned short* __restrict__ VfH,
    unsigned short* __restrict__ VfL) {
  const int widx = blockIdx.x * 4 + (threadIdx.x >> 6);  // 0..6143
  const int ct = widx % NCT;
  const int rt = widx / NCT;
  const int l = threadIdx.x & 63;
  const int lane15 = l & 15, g4 = l >> 4;
  const int row0 = rt * 16;

  const unsigned short* ah_p = hhi + (size_t)(row0 + lane15) * Dc + g4 * 8;
  const unsigned short* al_p = hlo + (size_t)(row0 + lane15) * Dc + g4 * 8;
  const unsigned short* bh_p = WfH + (size_t)ct * 2048 + l * 8;
  const unsigned short* bl_p = WfL + (size_t)ct * 2048 + l * 8;

  f32x4 acc = {0.f, 0.f, 0.f, 0.f};
#pragma unroll
  for (int kc = 0; kc < 4; ++kc) {
    const bf16x8 ah = *(const bf16x8*)(ah_p + kc * 32);
    const bf16x8 al = *(const bf16x8*)(al_p + kc * 32);
    const bf16x8 bh = *(const bf16x8*)(bh_p + kc * 512);
    const bf16x8 bl = *(const bf16x8*)(bl_p + kc * 512);
    acc = __builtin_amdgcn_mfma_f32_16x16x32_bf16(ah, bh, acc, 0, 0, 0);
    acc = __builtin_amdgcn_mfma_f32_16x16x32_bf16(ah, bl, acc, 0, 0, 0);
    acc = __builtin_amdgcn_mfma_f32_16x16x32_bf16(al, bh, acc, 0, 0, 0);
  }

  // C-layout: lane holds rows row0 + 4*g4 + i, col = lane15 (within tile ct)
  const int mat = ct >> 3, hh = ct & 7;
  const int b = row0 >> 11;
  const int g0 = row0 & 2047;
  const int bhh = b * Hc + hh;
  if (mat == 0) {
#pragma unroll
    for (int i = 0; i < 4; ++i)
      Q[((size_t)bhh * Gc + g0 + g4 * 4 + i) * Kc + lane15] = acc[i];
  } else if (mat == 1) {
#pragma unroll
    for (int i = 0; i < 4; ++i) {
      const size_t off = ((size_t)bhh * Gc + g0 + g4 * 4 + i) * Kc + lane15;
      const unsigned short hb = f2bf(acc[i]);
      Khi[off] = hb;
      Klo[off] = f2bf(acc[i] - bf2f(hb));
    }
  } else {
    const int c = g0 >> 4;  // row-tile == one kv-chunk
    u16x8 hv, lv;
#pragma unroll
    for (int i = 0; i < 4; ++i) {
      const unsigned short hb = f2bf(acc[i]);
      const unsigned short lb = f2bf(acc[i] - bf2f(hb));
      hv[i] = hb; hv[i + 4] = hb;   // duplicated for the PV k-slot layout
      lv[i] = lb; lv[i + 4] = lb;
    }
    const size_t off = ((size_t)(bhh * NCH + c) * 64 + l) * 8;
    *(u16x8*)(VfH + off) = hv;
    *(u16x8*)(VfL + off) = lv;
  }
}

// ---------------------------------------------------------------------------
// Flash attention, split-KV x4. One wave per (bh, qtile, split), 4 waves/block.
// S^T = mfma(K, Q) so the score C-layout feeds PV's B-operand directly.
// Defer-max (THR=8) skips cross-lane max + rescale in the steady state;
// per-lane partial row-sum reduced once at the end.
// ---------------------------------------------------------------------------
__global__ __launch_bounds__(256) void flash_kernel(
    const float* __restrict__ Q, const unsigned short* __restrict__ Khi,
    const unsigned short* __restrict__ Klo, const unsigned short* __restrict__ VfH,
    const unsigned short* __restrict__ VfL, float* __restrict__ part_o,
    float* __restrict__ part_ml) {
  const int gid = blockIdx.x * 4 + (threadIdx.x >> 6);  // 0..8191
  const int split = gid & 3;
  const int qt = gid >> 2;  // 0..2047
  const int bh = qt >> 7, qi = qt & 127;
  const int l = threadIdx.x & 63;
  const int lane15 = l & 15, g4 = l >> 4, dhalf = g4 & 1;

  const float* qp = Q + ((size_t)bh * Gc + qi * 16 + lane15) * Kc + 8 * dhalf;
  bf16x8 bqh, bql;
#pragma unroll
  for (int i = 0; i < 8; ++i) {
    const float x = qp[i];
    const unsigned short hb = f2bf(x);
    bqh[i] = (short)hb;
    bql[i] = (short)f2bf(x - bf2f(hb));
  }

  const unsigned short* kbase = (g4 >= 2 ? Klo : Khi) +
      (size_t)bh * Gc * Kc + lane15 * Kc + 8 * dhalf;
  const unsigned short* vfh = VfH + ((size_t)bh * NCH * 64 + l) * 8;
  const unsigned short* vfl = VfL + ((size_t)bh * NCH * 64 + l) * 8;

  const int c0 = split * CPS, c1 = c0 + CPS;
  f32x4 o = {0.f, 0.f, 0.f, 0.f};
  float run_max = -1e30f, lsum = 0.f;

  bf16x8 ak = *(const bf16x8*)(kbase + (size_t)c0 * 256);
  bf16x8 avh = *(const bf16x8*)(vfh + (size_t)c0 * 512);
  bf16x8 avl = *(const bf16x8*)(vfl + (size_t)c0 * 512);
  for (int c = c0; c < c1; ++c) {
    const int cn = (c + 1 < c1) ? c + 1 : c;  // last iter: redundant reload
    const bf16x8 ak_n = *(const bf16x8*)(kbase + (size_t)cn * 256);
    const bf16x8 avh_n = *(const bf16x8*)(vfh + (size_t)cn * 512);
    const bf16x8 avl_n = *(const bf16x8*)(vfl + (size_t)cn * 512);

    f32x4 s = {0.f, 0.f, 0.f, 0.f};
    s = __builtin_amdgcn_mfma_f32_16x16x32_bf16(ak, bql, s, 0, 0, 0);
    s = __builtin_amdgcn_mfma_f32_16x16x32_bf16(ak, bqh, s, 0, 0, 0);
    // s[i] = S^T[m = c*16 + 4*g4 + i][q = lane15]

    const float cm = fmaxf(fmaxf(s[0], s[1]), fmaxf(s[2], s[3]));
    if (!__all((int)(cm - run_max <= 8.0f))) {
      float fm = fmaxf(cm, __shfl_xor(cm, 16));
      fm = fmaxf(fm, __shfl_xor(fm, 32));
      const float nm = fmaxf(run_max, fm);
      const float corr = __expf(run_max - nm);  // first iter: exp(-inf)=0
      o[0] *= corr; o[1] *= corr; o[2] *= corr; o[3] *= corr;
      lsum *= corr;
      run_max = nm;
    }
    const float p0 = __expf(s[0] - run_max), p1 = __expf(s[1] - run_max);
    const float p2 = __expf(s[2] - run_max), p3 = __expf(s[3] - run_max);
    lsum += (p0 + p1) + (p2 + p3);

    bf16x8 bp;
    const unsigned short h0 = f2bf(p0), h1 = f2bf(p1);
    const unsigned short h2 = f2bf(p2), h3 = f2bf(p3);
    bp[0] = (short)h0; bp[1] = (short)h1; bp[2] = (short)h2; bp[3] = (short)h3;
    bp[4] = (short)f2bf(p0 - bf2f(h0));
    bp[5] = (short)f2bf(p1 - bf2f(h1));
    bp[6] = (short)f2bf(p2 - bf2f(h2));
    bp[7] = (short)f2bf(p3 - bf2f(h3));

    o = __builtin_amdgcn_mfma_f32_16x16x32_bf16(avh, bp, o, 0, 0, 0);
    o = __builtin_amdgcn_mfma_f32_16x16x32_bf16(avl, bp, o, 0, 0, 0);
    ak = ak_n; avh = avh_n; avl = avl_n;
  }

  float ls = lsum;
  ls += __shfl_xor(ls, 16);
  ls += __shfl_xor(ls, 32);

  const int pw = qt * SPLIT + split;
  *(f32x4*)(part_o + ((size_t)pw * 64 + l) * 4) = o;
  if (l < 16) {
    part_ml[pw * 32 + l * 2] = run_max;
    part_ml[pw * 32 + l * 2 + 1] = ls;
  }
}

// ---------------------------------------------------------------------------
// Merge the 4 split partials: out = sum_s e^{m_s-M} o_s / sum_s e^{m_s-M} l_s
// ---------------------------------------------------------------------------
__global__ __launch_bounds__(256) void combine_kernel(
    const float* __restrict__ part_o, const float* __restrict__ part_ml,
    float* __restrict__ out) {
  const int qt = blockIdx.x * 4 + (threadIdx.x >> 6);  // 0..2047
  const int l = threadIdx.x & 63;
  const int lane15 = l & 15, g4 = l >> 4;
  const int pw0 = qt * SPLIT;

  float m[SPLIT], lv[SPLIT];
#pragma unroll
  for (int s = 0; s < SPLIT; ++s) {
    const float2 ml = *(const float2*)(part_ml + (pw0 + s) * 32 + lane15 * 2);
    m[s] = ml.x;
    lv[s] = ml.y;
  }
  const float M = fmaxf(fmaxf(m[0], m[1]), fmaxf(m[2], m[3]));
  f32x4 acc = {0.f, 0.f, 0.f, 0.f};
  float den = 0.f;
#pragma unroll
  for (int s = 0; s < SPLIT; ++s) {
    const float w = __expf(m[s] - M);
    den += w * lv[s];
    const f32x4 po = *(const f32x4*)(part_o + ((size_t)(pw0 + s) * 64 + l) * 4);
    acc[0] += w * po[0]; acc[1] += w * po[1];
    acc[2] += w * po[2]; acc[3] += w * po[3];
  }
  const float inv = 1.0f / den;
  f32x4 res;
  res[0] = acc[0] * inv; res[1] = acc[1] * inv;
  res[2] = acc[2] * inv; res[3] = acc[3] * inv;
  const int bh = qt >> 7, qi = qt & 127;
  *(f32x4*)(out + ((size_t)bh * Gc + qi * 16 + lane15) * Kc + 4 * g4) = res;
}

extern "C" void kernel_launch(void* const* d_in, const int* in_sizes, int n_in,
                              void* d_out, int out_size, void* d_ws, size_t ws_size,
                              hipStream_t stream) {
  const float* h  = (const float*)d_in[0];
  const float* Wq = (const float*)d_in[1];
  const float* Wk = (const float*)d_in[2];
  const float* Wv = (const float*)d_in[3];
  float* out = (float*)d_out;

  char* ws = (char*)d_ws;
  float* Q            = (float*)(ws);                         // 2 MB
  unsigned short* Khi = (unsigned short*)(ws + (2u << 20));   // 1 MB
  unsigned short* Klo = (unsigned short*)(ws + (3u << 20));   // 1 MB
  unsigned short* VfH = (unsigned short*)(ws + (4u << 20));   // 2 MB
  unsigned short* VfL = (unsigned short*)(ws + (6u << 20));   // 2 MB
  unsigned short* hhi = (unsigned short*)(ws + (8u << 20));   // 1 MB
  unsigned short* hlo = (unsigned short*)(ws + (9u << 20));   // 1 MB
  unsigned short* WfH = (unsigned short*)(ws + (10u << 20));  // 96 KB
  unsigned short* WfL = (unsigned short*)(ws + (10u << 20) + (1u << 18));
  float* part_o  = (float*)(ws + (11u << 20));                // 8 MB
  float* part_ml = (float*)(ws + (19u << 20));                // 1 MB; total 20 MB

  hsplit_kernel<<<512, 256, 0, stream>>>(h, hhi, hlo);
  wsplit_kernel<<<24, 256, 0, stream>>>(Wq, Wk, Wv, WfH, WfL);
  proj_gemm_kernel<<<1536, 256, 0, stream>>>(hhi, hlo, WfH, WfL, Q, Khi, Klo,
                                             VfH, VfL);
  flash_kernel<<<2048, 256, 0, stream>>>(Q, Khi, Klo, VfH, VfL, part_o, part_ml);
  combine_kernel<<<512, 256, 0, stream>>>(part_o, part_ml, out);
}

// Round 3
// 102.368 us; speedup vs baseline: 1.6073x; 1.1807x over previous
//
#include <hip/hip_runtime.h>
#include <hip/hip_bf16.h>

// AttentionMechanismVaswani: B=2, G=2048, D=128, H=8, K=V=16
constexpr int Gc = 2048, Dc = 128, Hc = 8, Kc = 16;
constexpr int NCT = 24;       // col-tiles of the fused projection GEMM (8Q,8K,8V)
constexpr int NCH = 128;      // G/16 kv-chunks
constexpr int SPLIT = 4;      // kv-split factor
constexpr int CPS = NCH / SPLIT;

typedef __attribute__((ext_vector_type(8))) short bf16x8;
typedef __attribute__((ext_vector_type(4))) unsigned short u16x4;
typedef __attribute__((ext_vector_type(8))) unsigned short u16x8;
typedef __attribute__((ext_vector_type(4))) float f32x4;

// f32 -> bf16 (RNE) raw bits; hi/lo split gives ~2^-17 relative precision.
static __device__ __forceinline__ unsigned short f2bf(float f) {
  unsigned int u = __float_as_uint(f);
  u += 0x7FFFu + ((u >> 16) & 1u);
  return (unsigned short)(u >> 16);
}
static __device__ __forceinline__ float bf2f(unsigned short s) {
  return __uint_as_float(((unsigned int)s) << 16);
}
static __device__ __forceinline__ float fexp2(float x) {
#if __has_builtin(__builtin_amdgcn_exp2f)
  return __builtin_amdgcn_exp2f(x);
#else
  return exp2f(x);
#endif
}
// pack (lo,hi) -> one u32 of 2x bf16 via v_cvt_pk_bf16_f32
static __device__ __forceinline__ unsigned int pk_bf16(float lo, float hi) {
  __hip_bfloat162 b = __float22bfloat162_rn(make_float2(lo, hi));
  union { __hip_bfloat162 b2; unsigned int u; } cvt;
  cvt.b2 = b;
  return cvt.u;
}

// ---------------------------------------------------------------------------
// Prep: (blocks 0..511) split h [4096][128] f32 into bf16 hi/lo;
//       (blocks 512..535) pack W into B-fragment layout, hi/lo split.
// W_Q is pre-scaled by 0.25 * log2(e) so scores come out in log2 units.
// ---------------------------------------------------------------------------
__global__ __launch_bounds__(256) void prep_kernel(
    const float* __restrict__ h, const float* __restrict__ Wq,
    const float* __restrict__ Wk, const float* __restrict__ Wv,
    unsigned short* __restrict__ hhi, unsigned short* __restrict__ hlo,
    unsigned short* __restrict__ WfH, unsigned short* __restrict__ WfL) {
  if (blockIdx.x < 512) {
    const int t = blockIdx.x * 256 + threadIdx.x;  // 131072 threads, 4 elems
    const float4 v = *(const float4*)(h + (size_t)t * 4);
    const float a[4] = {v.x, v.y, v.z, v.w};
    u16x4 hi, lo;
#pragma unroll
    for (int i = 0; i < 4; ++i) {
      const unsigned short hb = f2bf(a[i]);
      hi[i] = hb;
      lo[i] = f2bf(a[i] - bf2f(hb));
    }
    *(u16x4*)(hhi + (size_t)t * 4) = hi;
    *(u16x4*)(hlo + (size_t)t * 4) = lo;
  } else {
    const int t = (blockIdx.x - 512) * 256 + threadIdx.x;  // 6144: (ct,kc,l)
    const int l = t & 63;
    const int kc = (t >> 6) & 3;
    const int ct = t >> 8;
    const int mat = ct >> 3, hh = ct & 7;
    const float* W = (mat == 0 ? Wq : (mat == 1 ? Wk : Wv)) + hh * (Dc * Kc);
    // fold compat_factor and log2(e) into W_Q
    const float scale = (mat == 0) ? 0.25f * 1.44269504088896f : 1.0f;
    const int col = l & 15, g4 = l >> 4;
    u16x8 hi, lo;
#pragma unroll
    for (int j = 0; j < 8; ++j) {
      const int d = kc * 32 + g4 * 8 + j;
      const float w = W[d * Kc + col] * scale;
      const unsigned short hb = f2bf(w);
      hi[j] = hb;
      lo[j] = f2bf(w - bf2f(hb));
    }
    *(u16x8*)(WfH + (size_t)t * 8) = hi;
    *(u16x8*)(WfL + (size_t)t * 8) = lo;
  }
}

// ---------------------------------------------------------------------------
// Fused projection GEMM: C[4096, 384] = h * [c*Wq | Wk | Wv] via split-bf16
// (hh*wh + hh*wl + hl*wh; lo*lo dropped, ~2^-18). One wave per 16x16 tile.
// Epilogues: Q -> f32; K -> hi/lo bf16 row-major; V -> merged [vh|vl] PV frag.
// ---------------------------------------------------------------------------
__global__ __launch_bounds__(256) void proj_gemm_kernel(
    const unsigned short* __restrict__ hhi, const unsigned short* __restrict__ hlo,
    const unsigned short* __restrict__ WfH, const unsigned short* __restrict__ WfL,
    float* __restrict__ Q, unsigned short* __restrict__ Khi,
    unsigned short* __restrict__ Klo, unsigned short* __restrict__ Vf) {
  const int widx = blockIdx.x * 4 + (threadIdx.x >> 6);  // 0..6143
  const int ct = widx % NCT;
  const int rt = widx / NCT;
  const int l = threadIdx.x & 63;
  const int lane15 = l & 15, g4 = l >> 4;
  const int row0 = rt * 16;

  const unsigned short* ah_p = hhi + (size_t)(row0 + lane15) * Dc + g4 * 8;
  const unsigned short* al_p = hlo + (size_t)(row0 + lane15) * Dc + g4 * 8;
  const unsigned short* bh_p = WfH + (size_t)ct * 2048 + l * 8;
  const unsigned short* bl_p = WfL + (size_t)ct * 2048 + l * 8;

  f32x4 acc = {0.f, 0.f, 0.f, 0.f};
#pragma unroll
  for (int kc = 0; kc < 4; ++kc) {
    const bf16x8 ah = *(const bf16x8*)(ah_p + kc * 32);
    const bf16x8 al = *(const bf16x8*)(al_p + kc * 32);
    const bf16x8 bh = *(const bf16x8*)(bh_p + kc * 512);
    const bf16x8 bl = *(const bf16x8*)(bl_p + kc * 512);
    acc = __builtin_amdgcn_mfma_f32_16x16x32_bf16(ah, bh, acc, 0, 0, 0);
    acc = __builtin_amdgcn_mfma_f32_16x16x32_bf16(ah, bl, acc, 0, 0, 0);
    acc = __builtin_amdgcn_mfma_f32_16x16x32_bf16(al, bh, acc, 0, 0, 0);
  }

  // C-layout: lane holds rows row0 + 4*g4 + i, col = lane15 (within tile ct)
  const int mat = ct >> 3, hh = ct & 7;
  const int b = row0 >> 11;
  const int g0 = row0 & 2047;
  const int bhh = b * Hc + hh;
  if (mat == 0) {
#pragma unroll
    for (int i = 0; i < 4; ++i)
      Q[((size_t)bhh * Gc + g0 + g4 * 4 + i) * Kc + lane15] = acc[i];
  } else if (mat == 1) {
#pragma unroll
    for (int i = 0; i < 4; ++i) {
      const size_t off = ((size_t)bhh * Gc + g0 + g4 * 4 + i) * Kc + lane15;
      const unsigned short hb = f2bf(acc[i]);
      Khi[off] = hb;
      Klo[off] = f2bf(acc[i] - bf2f(hb));
    }
  } else {
    const int c = g0 >> 4;  // row-tile == one kv-chunk
    u16x8 fv;
#pragma unroll
    for (int i = 0; i < 4; ++i) {
      const unsigned short hb = f2bf(acc[i]);
      fv[i] = hb;                           // k-slots 0-3: V-hi
      fv[i + 4] = f2bf(acc[i] - bf2f(hb));  // k-slots 4-7: V-lo
    }
    *(u16x8*)(Vf + ((size_t)(bhh * NCH + c) * 64 + l) * 8) = fv;
  }
}

// ---------------------------------------------------------------------------
// Flash attention, split-KV x4. One wave per (bh, qtile, split), 4 waves/block.
// S^T = mfma(K, Q), scores in log2 units; score C-layout feeds PV's B-operand.
// Defer-max (THR = 11.5 ~ 8 nats) skips cross-lane max + rescale steady-state.
// PV: one MFMA with A = [vh|vl], B = [ph|ph]  ->  ph*(vh+vl).
// ---------------------------------------------------------------------------
__global__ __launch_bounds__(256) void flash_kernel(
    const float* __restrict__ Q, const unsigned short* __restrict__ Khi,
    const unsigned short* __restrict__ Klo, const unsigned short* __restrict__ Vf,
    float* __restrict__ part_o, float* __restrict__ part_ml) {
  const int gid = blockIdx.x * 4 + (threadIdx.x >> 6);  // 0..8191
  const int split = gid & 3;
  const int qt = gid >> 2;  // 0..2047
  const int bh = qt >> 7, qi = qt & 127;
  const int l = threadIdx.x & 63;
  const int lane15 = l & 15, g4 = l >> 4, dhalf = g4 & 1;

  const float* qp = Q + ((size_t)bh * Gc + qi * 16 + lane15) * Kc + 8 * dhalf;
  bf16x8 bqh, bql;
#pragma unroll
  for (int i = 0; i < 8; ++i) {
    const float x = qp[i];
    const unsigned short hb = f2bf(x);
    bqh[i] = (short)hb;
    bql[i] = (short)f2bf(x - bf2f(hb));
  }

  const unsigned short* kbase = (g4 >= 2 ? Klo : Khi) +
      (size_t)bh * Gc * Kc + lane15 * Kc + 8 * dhalf;
  const unsigned short* vf = Vf + ((size_t)bh * NCH * 64 + l) * 8;

  const int c0 = split * CPS, c1 = c0 + CPS;
  f32x4 o = {0.f, 0.f, 0.f, 0.f};
  float run_max = -1e30f, lsum = 0.f;

#pragma unroll 4
  for (int c = c0; c < c1; ++c) {
    const bf16x8 ak = *(const bf16x8*)(kbase + (size_t)c * 256);
    const bf16x8 av = *(const bf16x8*)(vf + (size_t)c * 512);

    f32x4 s = {0.f, 0.f, 0.f, 0.f};
    s = __builtin_amdgcn_mfma_f32_16x16x32_bf16(ak, bql, s, 0, 0, 0);
    s = __builtin_amdgcn_mfma_f32_16x16x32_bf16(ak, bqh, s, 0, 0, 0);
    // s[i] = S^T[m = c*16 + 4*g4 + i][q = lane15], log2 units

    const float cm = fmaxf(fmaxf(s[0], s[1]), fmaxf(s[2], s[3]));
    if (!__all((int)(cm - run_max <= 11.5f))) {
      float fm = fmaxf(cm, __shfl_xor(cm, 16));
      fm = fmaxf(fm, __shfl_xor(fm, 32));
      const float nm = fmaxf(run_max, fm);
      const float corr = fexp2(run_max - nm);  // first iter: exp2(-huge) = 0
      o[0] *= corr; o[1] *= corr; o[2] *= corr; o[3] *= corr;
      lsum *= corr;
      run_max = nm;
    }
    const float p0 = fexp2(s[0] - run_max), p1 = fexp2(s[1] - run_max);
    const float p2 = fexp2(s[2] - run_max), p3 = fexp2(s[3] - run_max);
    lsum += (p0 + p1) + (p2 + p3);

    union { bf16x8 v; unsigned int w[4]; } bp;
    const unsigned int w01 = pk_bf16(p0, p1);
    const unsigned int w23 = pk_bf16(p2, p3);
    bp.w[0] = w01; bp.w[1] = w23; bp.w[2] = w01; bp.w[3] = w23;

    o = __builtin_amdgcn_mfma_f32_16x16x32_bf16(av, bp.v, o, 0, 0, 0);
  }

  float ls = lsum;
  ls += __shfl_xor(ls, 16);
  ls += __shfl_xor(ls, 32);

  const int pw = qt * SPLIT + split;
  *(f32x4*)(part_o + ((size_t)pw * 64 + l) * 4) = o;
  if (l < 16) {
    part_ml[pw * 32 + l * 2] = run_max;
    part_ml[pw * 32 + l * 2 + 1] = ls;
  }
}

// ---------------------------------------------------------------------------
// Merge the 4 split partials (m in log2 units):
//   out = sum_s 2^{m_s-M} o_s / sum_s 2^{m_s-M} l_s
// ---------------------------------------------------------------------------
__global__ __launch_bounds__(256) void combine_kernel(
    const float* __restrict__ part_o, const float* __restrict__ part_ml,
    float* __restrict__ out) {
  const int qt = blockIdx.x * 4 + (threadIdx.x >> 6);  // 0..2047
  const int l = threadIdx.x & 63;
  const int lane15 = l & 15, g4 = l >> 4;
  const int pw0 = qt * SPLIT;

  float m[SPLIT], lv[SPLIT];
#pragma unroll
  for (int s = 0; s < SPLIT; ++s) {
    const float2 ml = *(const float2*)(part_ml + (pw0 + s) * 32 + lane15 * 2);
    m[s] = ml.x;
    lv[s] = ml.y;
  }
  const float M = fmaxf(fmaxf(m[0], m[1]), fmaxf(m[2], m[3]));
  f32x4 acc = {0.f, 0.f, 0.f, 0.f};
  float den = 0.f;
#pragma unroll
  for (int s = 0; s < SPLIT; ++s) {
    const float w = fexp2(m[s] - M);
    den += w * lv[s];
    const f32x4 po = *(const f32x4*)(part_o + ((size_t)(pw0 + s) * 64 + l) * 4);
    acc[0] += w * po[0]; acc[1] += w * po[1];
    acc[2] += w * po[2]; acc[3] += w * po[3];
  }
  const float inv = 1.0f / den;
  f32x4 res;
  res[0] = acc[0] * inv; res[1] = acc[1] * inv;
  res[2] = acc[2] * inv; res[3] = acc[3] * inv;
  const int bh = qt >> 7, qi = qt & 127;
  *(f32x4*)(out + ((size_t)bh * Gc + qi * 16 + lane15) * Kc + 4 * g4) = res;
}

extern "C" void kernel_launch(void* const* d_in, const int* in_sizes, int n_in,
                              void* d_out, int out_size, void* d_ws, size_t ws_size,
                              hipStream_t stream) {
  const float* h  = (const float*)d_in[0];
  const float* Wq = (const float*)d_in[1];
  const float* Wk = (const float*)d_in[2];
  const float* Wv = (const float*)d_in[3];
  float* out = (float*)d_out;

  char* ws = (char*)d_ws;
  float* Q            = (float*)(ws);                         // 2 MB
  unsigned short* Khi = (unsigned short*)(ws + (2u << 20));   // 1 MB
  unsigned short* Klo = (unsigned short*)(ws + (3u << 20));   // 1 MB
  unsigned short* Vf  = (unsigned short*)(ws + (4u << 20));   // 2 MB
  unsigned short* hhi = (unsigned short*)(ws + (6u << 20));   // 1 MB
  unsigned short* hlo = (unsigned short*)(ws + (7u << 20));   // 1 MB
  unsigned short* WfH = (unsigned short*)(ws + (8u << 20));   // 96 KB
  unsigned short* WfL = (unsigned short*)(ws + (8u << 20) + (1u << 18));
  float* part_o  = (float*)(ws + (9u << 20));                 // 8 MB
  float* part_ml = (float*)(ws + (17u << 20));                // 1 MB; total 18 MB

  prep_kernel<<<536, 256, 0, stream>>>(h, Wq, Wk, Wv, hhi, hlo, WfH, WfL);
  proj_gemm_kernel<<<1536, 256, 0, stream>>>(hhi, hlo, WfH, WfL, Q, Khi, Klo, Vf);
  flash_kernel<<<2048, 256, 0, stream>>>(Q, Khi, Klo, Vf, part_o, part_ml);
  combine_kernel<<<512, 256, 0, stream>>>(part_o, part_ml, out);
}

// Round 5
// 99.779 us; speedup vs baseline: 1.6489x; 1.0259x over previous
//
#include <hip/hip_runtime.h>
#include <hip/hip_bf16.h>

// AttentionMechanismVaswani: B=2, G=2048, D=128, H=8, K=V=16
constexpr int Gc = 2048, Dc = 128, Hc = 8, Kc = 16;
constexpr int NCT = 24;       // col-tiles of the fused projection GEMM (8Q,8K,8V)
constexpr int NCH = 128;      // G/16 kv-chunks
constexpr int SPLIT = 4;      // kv-split factor == waves per flash block
constexpr int CPS = NCH / SPLIT;

typedef __attribute__((ext_vector_type(8))) short bf16x8;
typedef __attribute__((ext_vector_type(4))) unsigned short u16x4;
typedef __attribute__((ext_vector_type(8))) unsigned short u16x8;
typedef __attribute__((ext_vector_type(4))) float f32x4;

// f32 -> bf16 (RNE) raw bits; hi/lo split gives ~2^-17 relative precision.
static __device__ __forceinline__ unsigned short f2bf(float f) {
  unsigned int u = __float_as_uint(f);
  u += 0x7FFFu + ((u >> 16) & 1u);
  return (unsigned short)(u >> 16);
}
static __device__ __forceinline__ float bf2f(unsigned short s) {
  return __uint_as_float(((unsigned int)s) << 16);
}
static __device__ __forceinline__ float fexp2(float x) {
#if __has_builtin(__builtin_amdgcn_exp2f)
  return __builtin_amdgcn_exp2f(x);
#else
  return exp2f(x);
#endif
}
// pack (lo,hi) -> one u32 of 2x bf16 via v_cvt_pk_bf16_f32
static __device__ __forceinline__ unsigned int pk_bf16(float lo, float hi) {
  __hip_bfloat162 b = __float22bfloat162_rn(make_float2(lo, hi));
  union { __hip_bfloat162 b2; unsigned int u; } cvt;
  cvt.b2 = b;
  return cvt.u;
}

// ---------------------------------------------------------------------------
// Prep: (blocks 0..511) split h [4096][128] f32 into bf16 hi/lo;
//       (blocks 512..535) pack W into B-fragment layout, hi/lo split.
// W_Q is pre-scaled by 0.25 * log2(e) so scores come out in log2 units.
// ---------------------------------------------------------------------------
__global__ __launch_bounds__(256) void prep_kernel(
    const float* __restrict__ h, const float* __restrict__ Wq,
    const float* __restrict__ Wk, const float* __restrict__ Wv,
    unsigned short* __restrict__ hhi, unsigned short* __restrict__ hlo,
    unsigned short* __restrict__ WfH, unsigned short* __restrict__ WfL) {
  if (blockIdx.x < 512) {
    const int t = blockIdx.x * 256 + threadIdx.x;  // 131072 threads, 4 elems
    const float4 v = *(const float4*)(h + (size_t)t * 4);
    const float a[4] = {v.x, v.y, v.z, v.w};
    u16x4 hi, lo;
#pragma unroll
    for (int i = 0; i < 4; ++i) {
      const unsigned short hb = f2bf(a[i]);
      hi[i] = hb;
      lo[i] = f2bf(a[i] - bf2f(hb));
    }
    *(u16x4*)(hhi + (size_t)t * 4) = hi;
    *(u16x4*)(hlo + (size_t)t * 4) = lo;
  } else {
    const int t = (blockIdx.x - 512) * 256 + threadIdx.x;  // 6144: (ct,kc,l)
    const int l = t & 63;
    const int kc = (t >> 6) & 3;
    const int ct = t >> 8;
    const int mat = ct >> 3, hh = ct & 7;
    const float* W = (mat == 0 ? Wq : (mat == 1 ? Wk : Wv)) + hh * (Dc * Kc);
    // fold compat_factor and log2(e) into W_Q
    const float scale = (mat == 0) ? 0.25f * 1.44269504088896f : 1.0f;
    const int col = l & 15, g4 = l >> 4;
    u16x8 hi, lo;
#pragma unroll
    for (int j = 0; j < 8; ++j) {
      const int d = kc * 32 + g4 * 8 + j;
      const float w = W[d * Kc + col] * scale;
      const unsigned short hb = f2bf(w);
      hi[j] = hb;
      lo[j] = f2bf(w - bf2f(hb));
    }
    *(u16x8*)(WfH + (size_t)t * 8) = hi;
    *(u16x8*)(WfL + (size_t)t * 8) = lo;
  }
}

// ---------------------------------------------------------------------------
// Fused projection GEMM: C[4096, 384] = h * [c*Wq | Wk | Wv] via split-bf16
// (hh*wh + hh*wl + hl*wh; lo*lo dropped, ~2^-18). One wave per 16x16 tile.
// Epilogues: Q -> f32; K -> hi/lo bf16 row-major; V -> merged [vh|vl] PV frag.
// ---------------------------------------------------------------------------
__global__ __launch_bounds__(256) void proj_gemm_kernel(
    const unsigned short* __restrict__ hhi, const unsigned short* __restrict__ hlo,
    const unsigned short* __restrict__ WfH, const unsigned short* __restrict__ WfL,
    float* __restrict__ Q, unsigned short* __restrict__ Khi,
    unsigned short* __restrict__ Klo, unsigned short* __restrict__ Vf) {
  const int widx = blockIdx.x * 4 + (threadIdx.x >> 6);  // 0..6143
  const int ct = widx % NCT;
  const int rt = widx / NCT;
  const int l = threadIdx.x & 63;
  const int lane15 = l & 15, g4 = l >> 4;
  const int row0 = rt * 16;

  const unsigned short* ah_p = hhi + (size_t)(row0 + lane15) * Dc + g4 * 8;
  const unsigned short* al_p = hlo + (size_t)(row0 + lane15) * Dc + g4 * 8;
  const unsigned short* bh_p = WfH + (size_t)ct * 2048 + l * 8;
  const unsigned short* bl_p = WfL + (size_t)ct * 2048 + l * 8;

  f32x4 acc = {0.f, 0.f, 0.f, 0.f};
#pragma unroll
  for (int kc = 0; kc < 4; ++kc) {
    const bf16x8 ah = *(const bf16x8*)(ah_p + kc * 32);
    const bf16x8 al = *(const bf16x8*)(al_p + kc * 32);
    const bf16x8 bh = *(const bf16x8*)(bh_p + kc * 512);
    const bf16x8 bl = *(const bf16x8*)(bl_p + kc * 512);
    acc = __builtin_amdgcn_mfma_f32_16x16x32_bf16(ah, bh, acc, 0, 0, 0);
    acc = __builtin_amdgcn_mfma_f32_16x16x32_bf16(ah, bl, acc, 0, 0, 0);
    acc = __builtin_amdgcn_mfma_f32_16x16x32_bf16(al, bh, acc, 0, 0, 0);
  }

  // C-layout: lane holds rows row0 + 4*g4 + i, col = lane15 (within tile ct)
  const int mat = ct >> 3, hh = ct & 7;
  const int b = row0 >> 11;
  const int g0 = row0 & 2047;
  const int bhh = b * Hc + hh;
  if (mat == 0) {
#pragma unroll
    for (int i = 0; i < 4; ++i)
      Q[((size_t)bhh * Gc + g0 + g4 * 4 + i) * Kc + lane15] = acc[i];
  } else if (mat == 1) {
#pragma unroll
    for (int i = 0; i < 4; ++i) {
      const size_t off = ((size_t)bhh * Gc + g0 + g4 * 4 + i) * Kc + lane15;
      const unsigned short hb = f2bf(acc[i]);
      Khi[off] = hb;
      Klo[off] = f2bf(acc[i] - bf2f(hb));
    }
  } else {
    const int c = g0 >> 4;  // row-tile == one kv-chunk
    u16x8 fv;
#pragma unroll
    for (int i = 0; i < 4; ++i) {
      const unsigned short hb = f2bf(acc[i]);
      fv[i] = hb;                           // k-slots 0-3: V-hi
      fv[i + 4] = f2bf(acc[i] - bf2f(hb));  // k-slots 4-7: V-lo
    }
    *(u16x8*)(Vf + ((size_t)(bhh * NCH + c) * 64 + l) * 8) = fv;
  }
}

// ---------------------------------------------------------------------------
// Flash attention with fused split-combine. Block = one q-tile; its 4 waves
// are the 4 KV-splits; partials merged through LDS, out written directly.
// S^T = mfma(K, Q), scores in log2 units; score C-layout feeds PV's B-operand.
// 2 chunks per iteration: one defer-max branch per 32 kv rows, two
// independent PV accumulators (o0/o1) to double ILP on the serial chain.
// ---------------------------------------------------------------------------
__global__ __launch_bounds__(256) void flash_kernel(
    const float* __restrict__ Q, const unsigned short* __restrict__ Khi,
    const unsigned short* __restrict__ Klo, const unsigned short* __restrict__ Vf,
    float* __restrict__ out) {
  __shared__ f32x4 lo_s[SPLIT][64];
  __shared__ float lml[SPLIT][16][2];

  const int qt = blockIdx.x;  // 0..2047
  const int split = threadIdx.x >> 6;
  const int bh = qt >> 7, qi = qt & 127;
  const int l = threadIdx.x & 63;
  const int lane15 = l & 15, g4 = l >> 4, dhalf = g4 & 1;

  const float* qp = Q + ((size_t)bh * Gc + qi * 16 + lane15) * Kc + 8 * dhalf;
  bf16x8 bqh, bql;
#pragma unroll
  for (int i = 0; i < 8; ++i) {
    const float x = qp[i];
    const unsigned short hb = f2bf(x);
    bqh[i] = (short)hb;
    bql[i] = (short)f2bf(x - bf2f(hb));
  }

  const unsigned short* kbase = (g4 >= 2 ? Klo : Khi) +
      (size_t)bh * Gc * Kc + lane15 * Kc + 8 * dhalf;
  const unsigned short* vf = Vf + ((size_t)bh * NCH * 64 + l) * 8;

  const int c0 = split * CPS;
  const f32x4 z = {0.f, 0.f, 0.f, 0.f};
  f32x4 o0 = z, o1 = z;
  float run_max = -1e30f, thr = -1e30f, lsum = 0.f;

#pragma unroll 2
  for (int it = 0; it < CPS / 2; ++it) {
    const int c = c0 + it * 2;
    const bf16x8 ak0 = *(const bf16x8*)(kbase + (size_t)c * 256);
    const bf16x8 ak1 = *(const bf16x8*)(kbase + (size_t)c * 256 + 256);
    const bf16x8 av0 = *(const bf16x8*)(vf + (size_t)c * 512);
    const bf16x8 av1 = *(const bf16x8*)(vf + (size_t)c * 512 + 512);

    f32x4 s0 = __builtin_amdgcn_mfma_f32_16x16x32_bf16(ak0, bql, z, 0, 0, 0);
    s0 = __builtin_amdgcn_mfma_f32_16x16x32_bf16(ak0, bqh, s0, 0, 0, 0);
    f32x4 s1 = __builtin_amdgcn_mfma_f32_16x16x32_bf16(ak1, bql, z, 0, 0, 0);
    s1 = __builtin_amdgcn_mfma_f32_16x16x32_bf16(ak1, bqh, s1, 0, 0, 0);
    // sX[i] = S^T[m = (c+X)*16 + 4*g4 + i][q = lane15], log2 units

    const float cm = fmaxf(fmaxf(fmaxf(s0[0], s0[1]), fmaxf(s0[2], s0[3])),
                           fmaxf(fmaxf(s1[0], s1[1]), fmaxf(s1[2], s1[3])));
    if (!__all((int)(cm <= thr))) {
      float fm = fmaxf(cm, __shfl_xor(cm, 16));
      fm = fmaxf(fm, __shfl_xor(fm, 32));
      const float nm = fmaxf(run_max, fm);
      const float corr = fexp2(run_max - nm);  // first iter: exp2(-huge) = 0
      o0[0] *= corr; o0[1] *= corr; o0[2] *= corr; o0[3] *= corr;
      o1[0] *= corr; o1[1] *= corr; o1[2] *= corr; o1[3] *= corr;
      lsum *= corr;
      run_max = nm;
      thr = nm + 11.5f;  // ~8 nats of defer-max headroom
    }
    const float p0 = fexp2(s0[0] - run_max), p1 = fexp2(s0[1] - run_max);
    const float p2 = fexp2(s0[2] - run_max), p3 = fexp2(s0[3] - run_max);
    const float p4 = fexp2(s1[0] - run_max), p5 = fexp2(s1[1] - run_max);
    const float p6 = fexp2(s1[2] - run_max), p7 = fexp2(s1[3] - run_max);
    lsum += ((p0 + p1) + (p2 + p3)) + ((p4 + p5) + (p6 + p7));

    union { bf16x8 v; unsigned int w[4]; } bp0, bp1;
    const unsigned int a01 = pk_bf16(p0, p1), a23 = pk_bf16(p2, p3);
    const unsigned int b01 = pk_bf16(p4, p5), b23 = pk_bf16(p6, p7);
    bp0.w[0] = a01; bp0.w[1] = a23; bp0.w[2] = a01; bp0.w[3] = a23;
    bp1.w[0] = b01; bp1.w[1] = b23; bp1.w[2] = b01; bp1.w[3] = b23;

    o0 = __builtin_amdgcn_mfma_f32_16x16x32_bf16(av0, bp0.v, o0, 0, 0, 0);
    o1 = __builtin_amdgcn_mfma_f32_16x16x32_bf16(av1, bp1.v, o1, 0, 0, 0);
  }

  f32x4 o;
  o[0] = o0[0] + o1[0]; o[1] = o0[1] + o1[1];
  o[2] = o0[2] + o1[2]; o[3] = o0[3] + o1[3];
  float ls = lsum;
  ls += __shfl_xor(ls, 16);
  ls += __shfl_xor(ls, 32);

  lo_s[split][l] = o;
  if (l < 16) {
    lml[split][l][0] = run_max;
    lml[split][l][1] = ls;
  }
  __syncthreads();

  if (threadIdx.x < 64) {  // wave 0 merges the 4 split partials
    float m[SPLIT], lv[SPLIT];
#pragma unroll
    for (int s = 0; s < SPLIT; ++s) {
      m[s] = lml[s][lane15][0];
      lv[s] = lml[s][lane15][1];
    }
    const float M = fmaxf(fmaxf(m[0], m[1]), fmaxf(m[2], m[3]));
    f32x4 acc = {0.f, 0.f, 0.f, 0.f};
    float den = 0.f;
#pragma unroll
    for (int s = 0; s < SPLIT; ++s) {
      const float w = fexp2(m[s] - M);
      den += w * lv[s];
      const f32x4 po = lo_s[s][l];
      acc[0] += w * po[0]; acc[1] += w * po[1];
      acc[2] += w * po[2]; acc[3] += w * po[3];
    }
    const float inv = 1.0f / den;
    f32x4 res;
    res[0] = acc[0] * inv; res[1] = acc[1] * inv;
    res[2] = acc[2] * inv; res[3] = acc[3] * inv;
    *(f32x4*)(out + ((size_t)bh * Gc + qi * 16 + lane15) * Kc + 4 * g4) = res;
  }
}

extern "C" void kernel_launch(void* const* d_in, const int* in_sizes, int n_in,
                              void* d_out, int out_size, void* d_ws, size_t ws_size,
                              hipStream_t stream) {
  const float* h  = (const float*)d_in[0];
  const float* Wq = (const float*)d_in[1];
  const float* Wk = (const float*)d_in[2];
  const float* Wv = (const float*)d_in[3];
  float* out = (float*)d_out;

  char* ws = (char*)d_ws;
  float* Q            = (float*)(ws);                         // 2 MB
  unsigned short* Khi = (unsigned short*)(ws + (2u << 20));   // 1 MB
  unsigned short* Klo = (unsigned short*)(ws + (3u << 20));   // 1 MB
  unsigned short* Vf  = (unsigned short*)(ws + (4u << 20));   // 2 MB
  unsigned short* hhi = (unsigned short*)(ws + (6u << 20));   // 1 MB
  unsigned short* hlo = (unsigned short*)(ws + (7u << 20));   // 1 MB
  unsigned short* WfH = (unsigned short*)(ws + (8u << 20));   // 96 KB
  unsigned short* WfL = (unsigned short*)(ws + (8u << 20) + (1u << 18));

  prep_kernel<<<536, 256, 0, stream>>>(h, Wq, Wk, Wv, hhi, hlo, WfH, WfL);
  proj_gemm_kernel<<<1536, 256, 0, stream>>>(hhi, hlo, WfH, WfL, Q, Khi, Klo, Vf);
  flash_kernel<<<2048, 256, 0, stream>>>(Q, Khi, Klo, Vf, out);
}

// Round 7
// 98.925 us; speedup vs baseline: 1.6632x; 1.0086x over previous
//
#include <hip/hip_runtime.h>
#include <hip/hip_bf16.h>

// AttentionMechanismVaswani: B=2, G=2048, D=128, H=8, K=V=16
constexpr int Gc = 2048, Dc = 128, Hc = 8, Kc = 16;
constexpr int NCT = 24;       // col-tiles of the fused projection GEMM (8Q,8K,8V)
constexpr int NCH = 128;      // G/16 kv-chunks
constexpr int SPLIT = 8;      // kv-split factor == waves per flash block
constexpr int QPW = 2;        // q-tiles per wave (K/V loads amortized over both)
constexpr int CPS = NCH / SPLIT;  // 16 chunks per wave

typedef __attribute__((ext_vector_type(8))) short bf16x8;
typedef __attribute__((ext_vector_type(4))) unsigned short u16x4;
typedef __attribute__((ext_vector_type(8))) unsigned short u16x8;
typedef __attribute__((ext_vector_type(4))) float f32x4;

// f32 -> bf16 (RNE) raw bits; hi/lo split gives ~2^-17 relative precision.
static __device__ __forceinline__ unsigned short f2bf(float f) {
  unsigned int u = __float_as_uint(f);
  u += 0x7FFFu + ((u >> 16) & 1u);
  return (unsigned short)(u >> 16);
}
static __device__ __forceinline__ float bf2f(unsigned short s) {
  return __uint_as_float(((unsigned int)s) << 16);
}
static __device__ __forceinline__ float fexp2(float x) {
#if __has_builtin(__builtin_amdgcn_exp2f)
  return __builtin_amdgcn_exp2f(x);
#else
  return exp2f(x);
#endif
}
// pack (lo,hi) -> one u32 of 2x bf16 via v_cvt_pk_bf16_f32
static __device__ __forceinline__ unsigned int pk_bf16(float lo, float hi) {
  __hip_bfloat162 b = __float22bfloat162_rn(make_float2(lo, hi));
  union { __hip_bfloat162 b2; unsigned int u; } cvt;
  cvt.b2 = b;
  return cvt.u;
}

// ---------------------------------------------------------------------------
// Prep: (blocks 0..511) split h [4096][128] f32 into bf16 hi/lo;
//       (blocks 512..535) pack W into B-fragment layout, hi/lo split.
// W_Q is pre-scaled by 0.25 * log2(e) so scores come out in log2 units.
// ---------------------------------------------------------------------------
__global__ __launch_bounds__(256) void prep_kernel(
    const float* __restrict__ h, const float* __restrict__ Wq,
    const float* __restrict__ Wk, const float* __restrict__ Wv,
    unsigned short* __restrict__ hhi, unsigned short* __restrict__ hlo,
    unsigned short* __restrict__ WfH, unsigned short* __restrict__ WfL) {
  if (blockIdx.x < 512) {
    const int t = blockIdx.x * 256 + threadIdx.x;  // 131072 threads, 4 elems
    const float4 v = *(const float4*)(h + (size_t)t * 4);
    const float a[4] = {v.x, v.y, v.z, v.w};
    u16x4 hi, lo;
#pragma unroll
    for (int i = 0; i < 4; ++i) {
      const unsigned short hb = f2bf(a[i]);
      hi[i] = hb;
      lo[i] = f2bf(a[i] - bf2f(hb));
    }
    *(u16x4*)(hhi + (size_t)t * 4) = hi;
    *(u16x4*)(hlo + (size_t)t * 4) = lo;
  } else {
    const int t = (blockIdx.x - 512) * 256 + threadIdx.x;  // 6144: (ct,kc,l)
    const int l = t & 63;
    const int kc = (t >> 6) & 3;
    const int ct = t >> 8;
    const int mat = ct >> 3, hh = ct & 7;
    const float* W = (mat == 0 ? Wq : (mat == 1 ? Wk : Wv)) + hh * (Dc * Kc);
    // fold compat_factor and log2(e) into W_Q
    const float scale = (mat == 0) ? 0.25f * 1.44269504088896f : 1.0f;
    const int col = l & 15, g4 = l >> 4;
    u16x8 hi, lo;
#pragma unroll
    for (int j = 0; j < 8; ++j) {
      const int d = kc * 32 + g4 * 8 + j;
      const float w = W[d * Kc + col] * scale;
      const unsigned short hb = f2bf(w);
      hi[j] = hb;
      lo[j] = f2bf(w - bf2f(hb));
    }
    *(u16x8*)(WfH + (size_t)t * 8) = hi;
    *(u16x8*)(WfL + (size_t)t * 8) = lo;
  }
}

// ---------------------------------------------------------------------------
// Fused projection GEMM: C[4096, 384] = h * [c*Wq | Wk | Wv] via split-bf16
// (hh*wh + hh*wl + hl*wh; lo*lo dropped, ~2^-18). One wave per 16x16 tile.
// Epilogues: Q -> f32; K -> hi/lo bf16 row-major; V -> merged [vh|vl] PV frag.
// ---------------------------------------------------------------------------
__global__ __launch_bounds__(256) void proj_gemm_kernel(
    const unsigned short* __restrict__ hhi, const unsigned short* __restrict__ hlo,
    const unsigned short* __restrict__ WfH, const unsigned short* __restrict__ WfL,
    float* __restrict__ Q, unsigned short* __restrict__ Khi,
    unsigned short* __restrict__ Klo, unsigned short* __restrict__ Vf) {
  const int widx = blockIdx.x * 4 + (threadIdx.x >> 6);  // 0..6143
  const int ct = widx % NCT;
  const int rt = widx / NCT;
  const int l = threadIdx.x & 63;
  const int lane15 = l & 15, g4 = l >> 4;
  const int row0 = rt * 16;

  const unsigned short* ah_p = hhi + (size_t)(row0 + lane15) * Dc + g4 * 8;
  const unsigned short* al_p = hlo + (size_t)(row0 + lane15) * Dc + g4 * 8;
  const unsigned short* bh_p = WfH + (size_t)ct * 2048 + l * 8;
  const unsigned short* bl_p = WfL + (size_t)ct * 2048 + l * 8;

  f32x4 acc = {0.f, 0.f, 0.f, 0.f};
#pragma unroll
  for (int kc = 0; kc < 4; ++kc) {
    const bf16x8 ah = *(const bf16x8*)(ah_p + kc * 32);
    const bf16x8 al = *(const bf16x8*)(al_p + kc * 32);
    const bf16x8 bh = *(const bf16x8*)(bh_p + kc * 512);
    const bf16x8 bl = *(const bf16x8*)(bl_p + kc * 512);
    acc = __builtin_amdgcn_mfma_f32_16x16x32_bf16(ah, bh, acc, 0, 0, 0);
    acc = __builtin_amdgcn_mfma_f32_16x16x32_bf16(ah, bl, acc, 0, 0, 0);
    acc = __builtin_amdgcn_mfma_f32_16x16x32_bf16(al, bh, acc, 0, 0, 0);
  }

  // C-layout: lane holds rows row0 + 4*g4 + i, col = lane15 (within tile ct)
  const int mat = ct >> 3, hh = ct & 7;
  const int b = row0 >> 11;
  const int g0 = row0 & 2047;
  const int bhh = b * Hc + hh;
  if (mat == 0) {
#pragma unroll
    for (int i = 0; i < 4; ++i)
      Q[((size_t)bhh * Gc + g0 + g4 * 4 + i) * Kc + lane15] = acc[i];
  } else if (mat == 1) {
#pragma unroll
    for (int i = 0; i < 4; ++i) {
      const size_t off = ((size_t)bhh * Gc + g0 + g4 * 4 + i) * Kc + lane15;
      const unsigned short hb = f2bf(acc[i]);
      Khi[off] = hb;
      Klo[off] = f2bf(acc[i] - bf2f(hb));
    }
  } else {
    const int c = g0 >> 4;  // row-tile == one kv-chunk
    u16x8 fv;
#pragma unroll
    for (int i = 0; i < 4; ++i) {
      const unsigned short hb = f2bf(acc[i]);
      fv[i] = hb;                           // k-slots 0-3: V-hi
      fv[i + 4] = f2bf(acc[i] - bf2f(hb));  // k-slots 4-7: V-lo
    }
    *(u16x8*)(Vf + ((size_t)(bhh * NCH + c) * 64 + l) * 8) = fv;
  }
}

// ---------------------------------------------------------------------------
// Flash attention v3: 2 q-tiles per wave, 8-way KV split, fused combine.
// Block = 8 waves = the 8 splits of one q-tile PAIR; each K/V chunk load
// feeds both q-tiles (halves L2 traffic vs 1 qt/wave). Partials merged
// through LDS; out written directly.
// S^T = mfma(K, Q), scores in log2 units; score C-layout feeds PV's B-operand.
// ---------------------------------------------------------------------------
__global__ __launch_bounds__(512) void flash_kernel(
    const float* __restrict__ Q, const unsigned short* __restrict__ Khi,
    const unsigned short* __restrict__ Klo, const unsigned short* __restrict__ Vf,
    float* __restrict__ out) {
  __shared__ f32x4 lo_s[SPLIT][QPW][64];   // 16 KB
  __shared__ float lml[SPLIT][QPW][16][2]; // 2 KB

  const int qg = blockIdx.x;            // 0..1023 q-tile pairs
  const int split = threadIdx.x >> 6;   // 0..7
  const int bh = qg >> 6;               // 64 pairs per (b,h)
  const int qi0 = (qg & 63) * QPW;
  const int l = threadIdx.x & 63;
  const int lane15 = l & 15, g4 = l >> 4, dhalf = g4 & 1;

  // Q fragments (B-operand) for both q-tiles
  bf16x8 bqh[QPW], bql[QPW];
#pragma unroll
  for (int t = 0; t < QPW; ++t) {
    const float* qp =
        Q + ((size_t)bh * Gc + (qi0 + t) * 16 + lane15) * Kc + 8 * dhalf;
#pragma unroll
    for (int i = 0; i < 8; ++i) {
      const float x = qp[i];
      const unsigned short hb = f2bf(x);
      bqh[t][i] = (short)hb;
      bql[t][i] = (short)f2bf(x - bf2f(hb));
    }
  }

  // K A-fragment: lane groups 0,1 read Khi (k-slots 0-15), groups 2,3 read
  // Klo (k-slots 16-31) -> mfma(ak, bql) + mfma(ak, bqh) = full K*Q.
  const unsigned short* kbase = (g4 >= 2 ? Klo : Khi) +
      (size_t)bh * Gc * Kc + lane15 * Kc + 8 * dhalf;
  const unsigned short* vf = Vf + ((size_t)bh * NCH * 64 + l) * 8;

  const int c0 = split * CPS;
  const f32x4 z = {0.f, 0.f, 0.f, 0.f};
  f32x4 o[QPW] = {z, z};
  float run_max[QPW] = {-1e30f, -1e30f};
  float thr[QPW] = {-1e30f, -1e30f};
  float lsum[QPW] = {0.f, 0.f};

  for (int c = c0; c < c0 + CPS; ++c) {
    const bf16x8 ak = *(const bf16x8*)(kbase + (size_t)c * 256);
    const bf16x8 av = *(const bf16x8*)(vf + (size_t)c * 512);

#pragma unroll
    for (int t = 0; t < QPW; ++t) {
      f32x4 s = __builtin_amdgcn_mfma_f32_16x16x32_bf16(ak, bql[t], z, 0, 0, 0);
      s = __builtin_amdgcn_mfma_f32_16x16x32_bf16(ak, bqh[t], s, 0, 0, 0);
      // s[i] = S^T[m = c*16 + 4*g4 + i][q = lane15], log2 units

      const float cm = fmaxf(fmaxf(s[0], s[1]), fmaxf(s[2], s[3]));
      if (!__all((int)(cm <= thr[t]))) {
        float fm = fmaxf(cm, __shfl_xor(cm, 16));
        fm = fmaxf(fm, __shfl_xor(fm, 32));
        const float nm = fmaxf(run_max[t], fm);
        const float corr = fexp2(run_max[t] - nm);  // 1st iter: exp2(-huge)=0
        o[t][0] *= corr; o[t][1] *= corr; o[t][2] *= corr; o[t][3] *= corr;
        lsum[t] *= corr;
        run_max[t] = nm;
        thr[t] = nm + 11.5f;  // ~8 nats of defer-max headroom
      }
      const float p0 = fexp2(s[0] - run_max[t]);
      const float p1 = fexp2(s[1] - run_max[t]);
      const float p2 = fexp2(s[2] - run_max[t]);
      const float p3 = fexp2(s[3] - run_max[t]);
      lsum[t] += (p0 + p1) + (p2 + p3);

      union { bf16x8 v; unsigned int w[4]; } bp;
      const unsigned int w01 = pk_bf16(p0, p1);
      const unsigned int w23 = pk_bf16(p2, p3);
      bp.w[0] = w01; bp.w[1] = w23; bp.w[2] = w01; bp.w[3] = w23;

      o[t] = __builtin_amdgcn_mfma_f32_16x16x32_bf16(av, bp.v, o[t], 0, 0, 0);
    }
  }

#pragma unroll
  for (int t = 0; t < QPW; ++t) {
    float ls = lsum[t];
    ls += __shfl_xor(ls, 16);
    ls += __shfl_xor(ls, 32);
    lo_s[split][t][l] = o[t];
    if (l < 16) {
      lml[split][t][l][0] = run_max[t];
      lml[split][t][l][1] = ls;
    }
  }
  __syncthreads();

  if (threadIdx.x < QPW * 64) {  // wave t merges q-tile qi0+t
    const int t = split;  // 0..QPW-1 here
    float m[SPLIT], lv[SPLIT];
#pragma unroll
    for (int s = 0; s < SPLIT; ++s) {
      m[s] = lml[s][t][lane15][0];
      lv[s] = lml[s][t][lane15][1];
    }
    float M = m[0];
#pragma unroll
    for (int s = 1; s < SPLIT; ++s) M = fmaxf(M, m[s]);
    f32x4 acc = {0.f, 0.f, 0.f, 0.f};
    float den = 0.f;
#pragma unroll
    for (int s = 0; s < SPLIT; ++s) {
      const float w = fexp2(m[s] - M);
      den += w * lv[s];
      const f32x4 po = lo_s[s][t][l];
      acc[0] += w * po[0]; acc[1] += w * po[1];
      acc[2] += w * po[2]; acc[3] += w * po[3];
    }
    const float inv = 1.0f / den;
    f32x4 res;
    res[0] = acc[0] * inv; res[1] = acc[1] * inv;
    res[2] = acc[2] * inv; res[3] = acc[3] * inv;
    *(f32x4*)(out + ((size_t)bh * Gc + (qi0 + t) * 16 + lane15) * Kc + 4 * g4) =
        res;
  }
}

extern "C" void kernel_launch(void* const* d_in, const int* in_sizes, int n_in,
                              void* d_out, int out_size, void* d_ws, size_t ws_size,
                              hipStream_t stream) {
  const float* h  = (const float*)d_in[0];
  const float* Wq = (const float*)d_in[1];
  const float* Wk = (const float*)d_in[2];
  const float* Wv = (const float*)d_in[3];
  float* out = (float*)d_out;

  char* ws = (char*)d_ws;
  float* Q            = (float*)(ws);                         // 2 MB
  unsigned short* Khi = (unsigned short*)(ws + (2u << 20));   // 1 MB
  unsigned short* Klo = (unsigned short*)(ws + (3u << 20));   // 1 MB
  unsigned short* Vf  = (unsigned short*)(ws + (4u << 20));   // 2 MB
  unsigned short* hhi = (unsigned short*)(ws + (6u << 20));   // 1 MB
  unsigned short* hlo = (unsigned short*)(ws + (7u << 20));   // 1 MB
  unsigned short* WfH = (unsigned short*)(ws + (8u << 20));   // 96 KB
  unsigned short* WfL = (unsigned short*)(ws + (8u << 20) + (1u << 18));

  prep_kernel<<<536, 256, 0, stream>>>(h, Wq, Wk, Wv, hhi, hlo, WfH, WfL);
  proj_gemm_kernel<<<1536, 256, 0, stream>>>(hhi, hlo, WfH, WfL, Q, Khi, Klo, Vf);
  flash_kernel<<<1024, 512, 0, stream>>>(Q, Khi, Klo, Vf, out);
}

// Round 9
// 96.171 us; speedup vs baseline: 1.7108x; 1.0286x over previous
//
#include <hip/hip_runtime.h>
#include <hip/hip_bf16.h>

// AttentionMechanismVaswani: B=2, G=2048, D=128, H=8, K=V=16
constexpr int Gc = 2048, Dc = 128, Hc = 8, Kc = 16;
constexpr int NCT = 24;       // proj col-tiles (8 Q, 8 K, 8 V)
constexpr int NCH = 128;      // G/16 kv-chunks
constexpr int SPLIT = 8;      // kv-split factor == waves per flash block
constexpr int QPW = 2;        // q-tiles per wave
constexpr int CPS = NCH / SPLIT;  // 16 chunks per wave

typedef __attribute__((ext_vector_type(8))) short bf16x8;
typedef __attribute__((ext_vector_type(8))) unsigned short u16x8;
typedef __attribute__((ext_vector_type(4))) float f32x4;

// f32 -> bf16 (RNE) raw bits; hi/lo split gives ~2^-17 relative precision.
static __device__ __forceinline__ unsigned short f2bf(float f) {
  unsigned int u = __float_as_uint(f);
  u += 0x7FFFu + ((u >> 16) & 1u);
  return (unsigned short)(u >> 16);
}
static __device__ __forceinline__ float bf2f(unsigned short s) {
  return __uint_as_float(((unsigned int)s) << 16);
}
static __device__ __forceinline__ float fexp2(float x) {
#if __has_builtin(__builtin_amdgcn_exp2f)
  return __builtin_amdgcn_exp2f(x);
#else
  return exp2f(x);
#endif
}
// guaranteed single-instruction pack: D.lo = bf16(a), D.hi = bf16(b)
static __device__ __forceinline__ unsigned int pk_bf16(float a, float b) {
  unsigned int r;
  asm("v_cvt_pk_bf16_f32 %0, %1, %2" : "=v"(r) : "v"(a), "v"(b));
  return r;
}

// ---------------------------------------------------------------------------
// Fused projection GEMM: C[4096, 384] = h * [c*Wq | Wk | Wv], reading h and W
// as f32 and splitting to bf16 hi/lo in-register (hh*wh + hh*wl + hl*wh;
// lo*lo dropped, ~2^-18). One wave per 16x16 output tile, 6144 waves.
// Epilogues: Q,K -> hi/lo bf16 row-major [bh][g][16];
//            V   -> merged [vh|vl] PV A-fragment [bh][chunk][64][8].
// W_Q pre-scaled by 0.25*log2(e) so scores come out in log2 units.
// ---------------------------------------------------------------------------
__global__ __launch_bounds__(256) void proj_gemm_kernel(
    const float* __restrict__ h, const float* __restrict__ Wq,
    const float* __restrict__ Wk, const float* __restrict__ Wv,
    unsigned short* __restrict__ Qhi, unsigned short* __restrict__ Qlo,
    unsigned short* __restrict__ Khi, unsigned short* __restrict__ Klo,
    unsigned short* __restrict__ Vf) {
  const int widx = blockIdx.x * 4 + (threadIdx.x >> 6);  // 0..6143
  const int ct = widx % NCT;
  const int rt = widx / NCT;
  const int l = threadIdx.x & 63;
  const int lane15 = l & 15, g4 = l >> 4;
  const int row0 = rt * 16;
  const int mat = ct >> 3, hh = ct & 7;

  const float* W = (mat == 0 ? Wq : (mat == 1 ? Wk : Wv)) + hh * (Dc * Kc);
  const float scale = (mat == 0) ? 0.25f * 1.44269504088896f : 1.0f;
  const float* hp = h + (size_t)(row0 + lane15) * Dc + g4 * 8;

  f32x4 acc = {0.f, 0.f, 0.f, 0.f};
#pragma unroll
  for (int kc = 0; kc < 4; ++kc) {
    // A fragment: h rows, f32 -> hi/lo bf16 in-register
    const float4 v0 = *(const float4*)(hp + kc * 32);
    const float4 v1 = *(const float4*)(hp + kc * 32 + 4);
    const float av[8] = {v0.x, v0.y, v0.z, v0.w, v1.x, v1.y, v1.z, v1.w};
    bf16x8 ah, al;
#pragma unroll
    for (int i = 0; i < 8; ++i) {
      const unsigned short hb = f2bf(av[i]);
      ah[i] = (short)hb;
      al[i] = (short)f2bf(av[i] - bf2f(hb));
    }
    // B fragment: W[d][col], d = kc*32 + g4*8 + j, col = lane15
    bf16x8 bh, bl;
#pragma unroll
    for (int j = 0; j < 8; ++j) {
      const float w = W[(kc * 32 + g4 * 8 + j) * Kc + lane15] * scale;
      const unsigned short hb = f2bf(w);
      bh[j] = (short)hb;
      bl[j] = (short)f2bf(w - bf2f(hb));
    }
    acc = __builtin_amdgcn_mfma_f32_16x16x32_bf16(ah, bh, acc, 0, 0, 0);
    acc = __builtin_amdgcn_mfma_f32_16x16x32_bf16(ah, bl, acc, 0, 0, 0);
    acc = __builtin_amdgcn_mfma_f32_16x16x32_bf16(al, bh, acc, 0, 0, 0);
  }

  // C-layout: lane holds rows row0 + 4*g4 + i, col = lane15 (within tile ct)
  const int b = row0 >> 11;
  const int g0 = row0 & 2047;
  const int bhh = b * Hc + hh;
  if (mat <= 1) {
    unsigned short* dhi = (mat == 0) ? Qhi : Khi;
    unsigned short* dlo = (mat == 0) ? Qlo : Klo;
#pragma unroll
    for (int i = 0; i < 4; ++i) {
      const size_t off = ((size_t)bhh * Gc + g0 + g4 * 4 + i) * Kc + lane15;
      const unsigned short hb = f2bf(acc[i]);
      dhi[off] = hb;
      dlo[off] = f2bf(acc[i] - bf2f(hb));
    }
  } else {
    const int c = g0 >> 4;  // row-tile == one kv-chunk
    u16x8 fv;
#pragma unroll
    for (int i = 0; i < 4; ++i) {
      const unsigned short hb = f2bf(acc[i]);
      fv[i] = hb;                           // k-slots 0-3: V-hi
      fv[i + 4] = f2bf(acc[i] - bf2f(hb));  // k-slots 4-7: V-lo
    }
    *(u16x8*)(Vf + ((size_t)(bhh * NCH + c) * 64 + l) * 8) = fv;
  }
}

// ---------------------------------------------------------------------------
// Flash attention: 2 q-tiles per wave, 8-way KV split, fused combine.
// Block = 8 waves = the 8 splits of one q-tile pair; each K/V chunk load
// feeds both q-tiles. Partials merged through LDS; out written directly.
// S^T = mfma(K, Q), scores in log2 units: K A-frag rows are kv, lane groups
// 0,1 take Khi (k-slots 0-15), groups 2,3 take Klo (16-31); B-frag = Q^T
// hi then lo, chained C. Score C-layout [m=4*g4+i][q=lane15] feeds PV's
// B-operand directly. Defer-max (11.5 in log2 ~ 8 nats) + lazy row-sum.
// ---------------------------------------------------------------------------
__global__ __launch_bounds__(512) void flash_kernel(
    const unsigned short* __restrict__ Qhi, const unsigned short* __restrict__ Qlo,
    const unsigned short* __restrict__ Khi, const unsigned short* __restrict__ Klo,
    const unsigned short* __restrict__ Vf, float* __restrict__ out) {
  __shared__ f32x4 lo_s[SPLIT][QPW][64];   // 16 KB
  __shared__ float lml[SPLIT][QPW][16][2]; // 2 KB

  const int qg = blockIdx.x;            // 0..1023 q-tile pairs
  const int split = threadIdx.x >> 6;   // 0..7
  const int bh = qg >> 6;               // 64 pairs per (b,h)
  const int qi0 = (qg & 63) * QPW;
  const int l = threadIdx.x & 63;
  const int lane15 = l & 15, g4 = l >> 4, dhalf = g4 & 1;

  // Q fragments (B-operand) for both q-tiles: direct bf16 hi/lo loads
  bf16x8 bqh[QPW], bql[QPW];
#pragma unroll
  for (int t = 0; t < QPW; ++t) {
    const size_t qoff =
        ((size_t)bh * Gc + (qi0 + t) * 16 + lane15) * Kc + 8 * dhalf;
    bqh[t] = *(const bf16x8*)(Qhi + qoff);
    bql[t] = *(const bf16x8*)(Qlo + qoff);
  }

  const unsigned short* kbase = (g4 >= 2 ? Klo : Khi) +
      (size_t)bh * Gc * Kc + lane15 * Kc + 8 * dhalf;
  const unsigned short* vf = Vf + ((size_t)bh * NCH * 64 + l) * 8;

  const int c0 = split * CPS;
  const f32x4 z = {0.f, 0.f, 0.f, 0.f};
  f32x4 o[QPW] = {z, z};
  float run_max[QPW] = {-1e30f, -1e30f};
  float thr[QPW] = {-1e30f, -1e30f};
  float lsum[QPW] = {0.f, 0.f};

  for (int c = c0; c < c0 + CPS; ++c) {
    const bf16x8 ak = *(const bf16x8*)(kbase + (size_t)c * 256);
    const bf16x8 av = *(const bf16x8*)(vf + (size_t)c * 512);

#pragma unroll
    for (int t = 0; t < QPW; ++t) {
      f32x4 s = __builtin_amdgcn_mfma_f32_16x16x32_bf16(ak, bql[t], z, 0, 0, 0);
      s = __builtin_amdgcn_mfma_f32_16x16x32_bf16(ak, bqh[t], s, 0, 0, 0);
      // s[i] = S^T[m = c*16 + 4*g4 + i][q = lane15], log2 units

      const float cm = fmaxf(fmaxf(s[0], s[1]), fmaxf(s[2], s[3]));
      if (!__all((int)(cm <= thr[t]))) {
        float fm = fmaxf(cm, __shfl_xor(cm, 16));
        fm = fmaxf(fm, __shfl_xor(fm, 32));
        const float nm = fmaxf(run_max[t], fm);
        const float corr = fexp2(run_max[t] - nm);  // 1st iter: exp2(-huge)=0
        o[t][0] *= corr; o[t][1] *= corr; o[t][2] *= corr; o[t][3] *= corr;
        lsum[t] *= corr;
        run_max[t] = nm;
        thr[t] = nm + 11.5f;  // ~8 nats of defer-max headroom
      }
      const float p0 = fexp2(s[0] - run_max[t]);
      const float p1 = fexp2(s[1] - run_max[t]);
      const float p2 = fexp2(s[2] - run_max[t]);
      const float p3 = fexp2(s[3] - run_max[t]);
      lsum[t] += (p0 + p1) + (p2 + p3);

      union { bf16x8 v; unsigned int w[4]; } bp;
      const unsigned int w01 = pk_bf16(p0, p1);
      const unsigned int w23 = pk_bf16(p2, p3);
      bp.w[0] = w01; bp.w[1] = w23; bp.w[2] = w01; bp.w[3] = w23;

      o[t] = __builtin_amdgcn_mfma_f32_16x16x32_bf16(av, bp.v, o[t], 0, 0, 0);
    }
  }

#pragma unroll
  for (int t = 0; t < QPW; ++t) {
    float ls = lsum[t];
    ls += __shfl_xor(ls, 16);
    ls += __shfl_xor(ls, 32);
    lo_s[split][t][l] = o[t];
    if (l < 16) {
      lml[split][t][l][0] = run_max[t];
      lml[split][t][l][1] = ls;
    }
  }
  __syncthreads();

  if (threadIdx.x < QPW * 64) {  // wave t merges q-tile qi0+t
    const int t = split;  // 0..QPW-1 here
    float m[SPLIT], lv[SPLIT];
#pragma unroll
    for (int s = 0; s < SPLIT; ++s) {
      m[s] = lml[s][t][lane15][0];
      lv[s] = lml[s][t][lane15][1];
    }
    float M = m[0];
#pragma unroll
    for (int s = 1; s < SPLIT; ++s) M = fmaxf(M, m[s]);
    f32x4 acc = {0.f, 0.f, 0.f, 0.f};
    float den = 0.f;
#pragma unroll
    for (int s = 0; s < SPLIT; ++s) {
      const float w = fexp2(m[s] - M);
      den += w * lv[s];
      const f32x4 po = lo_s[s][t][l];
      acc[0] += w * po[0]; acc[1] += w * po[1];
      acc[2] += w * po[2]; acc[3] += w * po[3];
    }
    const float inv = 1.0f / den;
    f32x4 res;
    res[0] = acc[0] * inv; res[1] = acc[1] * inv;
    res[2] = acc[2] * inv; res[3] = acc[3] * inv;
    *(f32x4*)(out + ((size_t)bh * Gc + (qi0 + t) * 16 + lane15) * Kc + 4 * g4) =
        res;
  }
}

extern "C" void kernel_launch(void* const* d_in, const int* in_sizes, int n_in,
                              void* d_out, int out_size, void* d_ws, size_t ws_size,
                              hipStream_t stream) {
  const float* h  = (const float*)d_in[0];
  const float* Wq = (const float*)d_in[1];
  const float* Wk = (const float*)d_in[2];
  const float* Wv = (const float*)d_in[3];
  float* out = (float*)d_out;

  char* ws = (char*)d_ws;
  unsigned short* Qhi = (unsigned short*)(ws);                // 1 MB
  unsigned short* Qlo = (unsigned short*)(ws + (1u << 20));   // 1 MB
  unsigned short* Khi = (unsigned short*)(ws + (2u << 20));   // 1 MB
  unsigned short* Klo = (unsigned short*)(ws + (3u << 20));   // 1 MB
  unsigned short* Vf  = (unsigned short*)(ws + (4u << 20));   // 2 MB

  proj_gemm_kernel<<<1536, 256, 0, stream>>>(h, Wq, Wk, Wv, Qhi, Qlo, Khi, Klo,
                                             Vf);
  flash_kernel<<<1024, 512, 0, stream>>>(Qhi, Qlo, Khi, Klo, Vf, out);
}

// Round 10
// 94.469 us; speedup vs baseline: 1.7416x; 1.0180x over previous
//
#include <hip/hip_runtime.h>
#include <hip/hip_bf16.h>

// AttentionMechanismVaswani: B=2, G=2048, D=128, H=8, K=V=16
constexpr int Gc = 2048, Dc = 128, Hc = 8, Kc = 16;
constexpr int NCT = 24;       // proj col-tiles (8 Q, 8 K, 8 V)
constexpr int NCH = 128;      // G/16 kv-chunks
constexpr int SPLIT = 8;      // kv-split factor == waves per flash block
constexpr int QPW = 2;        // q-tiles per wave
constexpr int CPS = NCH / SPLIT;  // 16 chunks per wave

typedef __attribute__((ext_vector_type(8))) short bf16x8;
typedef __attribute__((ext_vector_type(8))) unsigned short u16x8;
typedef __attribute__((ext_vector_type(4))) unsigned int u32x4;
typedef __attribute__((ext_vector_type(4))) float f32x4;

// f32 -> bf16 (RNE) raw bits; hi/lo split gives ~2^-17 relative precision.
static __device__ __forceinline__ unsigned short f2bf(float f) {
  unsigned int u = __float_as_uint(f);
  u += 0x7FFFu + ((u >> 16) & 1u);
  return (unsigned short)(u >> 16);
}
static __device__ __forceinline__ float bf2f(unsigned short s) {
  return __uint_as_float(((unsigned int)s) << 16);
}
static __device__ __forceinline__ float fexp2(float x) {
#if __has_builtin(__builtin_amdgcn_exp2f)
  return __builtin_amdgcn_exp2f(x);
#else
  return exp2f(x);
#endif
}
// guaranteed single-instruction pack: D.lo = bf16(a), D.hi = bf16(b)
static __device__ __forceinline__ unsigned int pk_bf16(float a, float b) {
  unsigned int r;
  asm("v_cvt_pk_bf16_f32 %0, %1, %2" : "=v"(r) : "v"(a), "v"(b));
  return r;
}

// ---------------------------------------------------------------------------
// Fused projection GEMM: C[4096, 384] = h * [c*Wq | Wk | Wv], reading h and W
// as f32 and splitting to bf16 hi/lo in-register (hh*wh + hh*wl + hl*wh;
// lo*lo dropped, ~2^-18). One wave per 16x16 output tile, 6144 waves.
// Epilogues: Q,K -> hi/lo bf16 row-major [bh][g][16];
//            V   -> merged [vh|vl] PV A-fragment [bh][chunk][64][8].
// W_Q pre-scaled by 0.25*log2(e) so scores come out in log2 units.
// ---------------------------------------------------------------------------
__global__ __launch_bounds__(256) void proj_gemm_kernel(
    const float* __restrict__ h, const float* __restrict__ Wq,
    const float* __restrict__ Wk, const float* __restrict__ Wv,
    unsigned short* __restrict__ Qhi, unsigned short* __restrict__ Qlo,
    unsigned short* __restrict__ Khi, unsigned short* __restrict__ Klo,
    unsigned short* __restrict__ Vf) {
  const int widx = blockIdx.x * 4 + (threadIdx.x >> 6);  // 0..6143
  const int ct = widx % NCT;
  const int rt = widx / NCT;
  const int l = threadIdx.x & 63;
  const int lane15 = l & 15, g4 = l >> 4;
  const int row0 = rt * 16;
  const int mat = ct >> 3, hh = ct & 7;

  const float* W = (mat == 0 ? Wq : (mat == 1 ? Wk : Wv)) + hh * (Dc * Kc);
  const float scale = (mat == 0) ? 0.25f * 1.44269504088896f : 1.0f;
  const float* hp = h + (size_t)(row0 + lane15) * Dc + g4 * 8;

  f32x4 acc = {0.f, 0.f, 0.f, 0.f};
#pragma unroll
  for (int kc = 0; kc < 4; ++kc) {
    // A fragment: h rows, f32 -> hi/lo bf16 in-register
    const float4 v0 = *(const float4*)(hp + kc * 32);
    const float4 v1 = *(const float4*)(hp + kc * 32 + 4);
    const float av[8] = {v0.x, v0.y, v0.z, v0.w, v1.x, v1.y, v1.z, v1.w};
    bf16x8 ah, al;
#pragma unroll
    for (int i = 0; i < 8; ++i) {
      const unsigned short hb = f2bf(av[i]);
      ah[i] = (short)hb;
      al[i] = (short)f2bf(av[i] - bf2f(hb));
    }
    // B fragment: W[d][col], d = kc*32 + g4*8 + j, col = lane15
    bf16x8 bh, bl;
#pragma unroll
    for (int j = 0; j < 8; ++j) {
      const float w = W[(kc * 32 + g4 * 8 + j) * Kc + lane15] * scale;
      const unsigned short hb = f2bf(w);
      bh[j] = (short)hb;
      bl[j] = (short)f2bf(w - bf2f(hb));
    }
    acc = __builtin_amdgcn_mfma_f32_16x16x32_bf16(ah, bh, acc, 0, 0, 0);
    acc = __builtin_amdgcn_mfma_f32_16x16x32_bf16(ah, bl, acc, 0, 0, 0);
    acc = __builtin_amdgcn_mfma_f32_16x16x32_bf16(al, bh, acc, 0, 0, 0);
  }

  // C-layout: lane holds rows row0 + 4*g4 + i, col = lane15 (within tile ct)
  const int b = row0 >> 11;
  const int g0 = row0 & 2047;
  const int bhh = b * Hc + hh;
  if (mat <= 1) {
    unsigned short* dhi = (mat == 0) ? Qhi : Khi;
    unsigned short* dlo = (mat == 0) ? Qlo : Klo;
#pragma unroll
    for (int i = 0; i < 4; ++i) {
      const size_t off = ((size_t)bhh * Gc + g0 + g4 * 4 + i) * Kc + lane15;
      const unsigned short hb = f2bf(acc[i]);
      dhi[off] = hb;
      dlo[off] = f2bf(acc[i] - bf2f(hb));
    }
  } else {
    const int c = g0 >> 4;  // row-tile == one kv-chunk
    u16x8 fv;
#pragma unroll
    for (int i = 0; i < 4; ++i) {
      const unsigned short hb = f2bf(acc[i]);
      fv[i] = hb;                           // k-slots 0-3: V-hi
      fv[i + 4] = f2bf(acc[i] - bf2f(hb));  // k-slots 4-7: V-lo
    }
    *(u16x8*)(Vf + ((size_t)(bhh * NCH + c) * 64 + l) * 8) = fv;
  }
}

// ---------------------------------------------------------------------------
// Flash attention: 2 q-tiles per wave, 8-way KV split, fused combine.
// Block = 8 waves = the 8 splits of one q-tile pair; each K/V chunk load
// feeds both q-tiles. Partials merged through LDS; out written directly.
// S^T = mfma(K, Q), scores in log2 units: K A-frag rows are kv, lane groups
// 0,1 take Khi (k-slots 0-15), groups 2,3 take Klo (16-31); B-frag = Q^T
// hi then lo, chained C. Score C-layout [m=4*g4+i][q=lane15] feeds PV's
// B-operand directly. SHARED defer-max state (one run_max/thr/branch per
// chunk for both q-tiles — numerically safe: shared max only changes the
// common reference point, P stays bounded by 2^11.5).
// __launch_bounds__(512, 6): cap VGPR ~85 -> 3 blocks/CU (24 waves/CU).
// ---------------------------------------------------------------------------
__global__ __launch_bounds__(512, 6) void flash_kernel(
    const unsigned short* __restrict__ Qhi, const unsigned short* __restrict__ Qlo,
    const unsigned short* __restrict__ Khi, const unsigned short* __restrict__ Klo,
    const unsigned short* __restrict__ Vf, float* __restrict__ out) {
  __shared__ f32x4 lo_s[SPLIT][QPW][64];   // 16 KB
  __shared__ float lml[SPLIT][QPW][16][2]; // 2 KB

  const int qg = blockIdx.x;            // 0..1023 q-tile pairs
  const int split = threadIdx.x >> 6;   // 0..7
  const int bh = qg >> 6;               // 64 pairs per (b,h)
  const int qi0 = (qg & 63) * QPW;
  const int l = threadIdx.x & 63;
  const int lane15 = l & 15, g4 = l >> 4, dhalf = g4 & 1;

  // Q fragments (B-operand) for both q-tiles: direct bf16 hi/lo loads
  bf16x8 bqh[QPW], bql[QPW];
#pragma unroll
  for (int t = 0; t < QPW; ++t) {
    const size_t qoff =
        ((size_t)bh * Gc + (qi0 + t) * 16 + lane15) * Kc + 8 * dhalf;
    bqh[t] = *(const bf16x8*)(Qhi + qoff);
    bql[t] = *(const bf16x8*)(Qlo + qoff);
  }

  const unsigned short* kbase = (g4 >= 2 ? Klo : Khi) +
      (size_t)bh * Gc * Kc + lane15 * Kc + 8 * dhalf + (size_t)split * CPS * 256;
  const unsigned short* vbase =
      Vf + ((size_t)bh * NCH * 64 + l) * 8 + (size_t)split * CPS * 512;

  const f32x4 z = {0.f, 0.f, 0.f, 0.f};
  f32x4 o[QPW] = {z, z};
  float run_max = -1e30f, thr = -1e30f;
  float lsum[QPW] = {0.f, 0.f};

#pragma unroll 4
  for (int c = 0; c < CPS; ++c) {
    const bf16x8 ak = *(const bf16x8*)(kbase + (size_t)c * 256);
    const bf16x8 av = *(const bf16x8*)(vbase + (size_t)c * 512);

    // QK^T for both tiles first (independent MFMA chains), then one shared
    // defer-max decision.
    f32x4 s[QPW];
#pragma unroll
    for (int t = 0; t < QPW; ++t) {
      f32x4 tmp = __builtin_amdgcn_mfma_f32_16x16x32_bf16(ak, bql[t], z, 0, 0, 0);
      s[t] = __builtin_amdgcn_mfma_f32_16x16x32_bf16(ak, bqh[t], tmp, 0, 0, 0);
      // s[t][i] = S^T[m = c*16 + 4*g4 + i][q = lane15], log2 units
    }

    float cm = fmaxf(fmaxf(s[0][0], s[0][1]), fmaxf(s[0][2], s[0][3]));
    cm = fmaxf(cm, fmaxf(fmaxf(s[1][0], s[1][1]), fmaxf(s[1][2], s[1][3])));
    if (!__all((int)(cm <= thr))) {
      float fm = fmaxf(cm, __shfl_xor(cm, 16));
      fm = fmaxf(fm, __shfl_xor(fm, 32));
      const float nm = fmaxf(run_max, fm);
      const float corr = fexp2(run_max - nm);  // 1st iter: exp2(-huge)=0
#pragma unroll
      for (int t = 0; t < QPW; ++t) {
        o[t][0] *= corr; o[t][1] *= corr; o[t][2] *= corr; o[t][3] *= corr;
        lsum[t] *= corr;
      }
      run_max = nm;
      thr = nm + 11.5f;  // ~8 nats of defer-max headroom
    }

#pragma unroll
    for (int t = 0; t < QPW; ++t) {
      const float p0 = fexp2(s[t][0] - run_max);
      const float p1 = fexp2(s[t][1] - run_max);
      const float p2 = fexp2(s[t][2] - run_max);
      const float p3 = fexp2(s[t][3] - run_max);
      lsum[t] += (p0 + p1) + (p2 + p3);

      const unsigned int w01 = pk_bf16(p0, p1);
      const unsigned int w23 = pk_bf16(p2, p3);
      const u32x4 bpv = {w01, w23, w01, w23};
      const bf16x8 bp = __builtin_bit_cast(bf16x8, bpv);
      o[t] = __builtin_amdgcn_mfma_f32_16x16x32_bf16(av, bp, o[t], 0, 0, 0);
    }
  }

#pragma unroll
  for (int t = 0; t < QPW; ++t) {
    float ls = lsum[t];
    ls += __shfl_xor(ls, 16);
    ls += __shfl_xor(ls, 32);
    lo_s[split][t][l] = o[t];
    if (l < 16) {
      lml[split][t][l][0] = run_max;
      lml[split][t][l][1] = ls;
    }
  }
  __syncthreads();

  if (threadIdx.x < QPW * 64) {  // wave t merges q-tile qi0+t
    const int t = split;  // 0..QPW-1 here
    float m[SPLIT], lv[SPLIT];
#pragma unroll
    for (int s = 0; s < SPLIT; ++s) {
      m[s] = lml[s][t][lane15][0];
      lv[s] = lml[s][t][lane15][1];
    }
    float M = m[0];
#pragma unroll
    for (int s = 1; s < SPLIT; ++s) M = fmaxf(M, m[s]);
    f32x4 acc = {0.f, 0.f, 0.f, 0.f};
    float den = 0.f;
#pragma unroll
    for (int s = 0; s < SPLIT; ++s) {
      const float w = fexp2(m[s] - M);
      den += w * lv[s];
      const f32x4 po = lo_s[s][t][l];
      acc[0] += w * po[0]; acc[1] += w * po[1];
      acc[2] += w * po[2]; acc[3] += w * po[3];
    }
    const float inv = 1.0f / den;
    f32x4 res;
    res[0] = acc[0] * inv; res[1] = acc[1] * inv;
    res[2] = acc[2] * inv; res[3] = acc[3] * inv;
    *(f32x4*)(out + ((size_t)bh * Gc + (qi0 + t) * 16 + lane15) * Kc + 4 * g4) =
        res;
  }
}

extern "C" void kernel_launch(void* const* d_in, const int* in_sizes, int n_in,
                              void* d_out, int out_size, void* d_ws, size_t ws_size,
                              hipStream_t stream) {
  const float* h  = (const float*)d_in[0];
  const float* Wq = (const float*)d_in[1];
  const float* Wk = (const float*)d_in[2];
  const float* Wv = (const float*)d_in[3];
  float* out = (float*)d_out;

  char* ws = (char*)d_ws;
  unsigned short* Qhi = (unsigned short*)(ws);                // 1 MB
  unsigned short* Qlo = (unsigned short*)(ws + (1u << 20));   // 1 MB
  unsigned short* Khi = (unsigned short*)(ws + (2u << 20));   // 1 MB
  unsigned short* Klo = (unsigned short*)(ws + (3u << 20));   // 1 MB
  unsigned short* Vf  = (unsigned short*)(ws + (4u << 20));   // 2 MB

  proj_gemm_kernel<<<1536, 256, 0, stream>>>(h, Wq, Wk, Wv, Qhi, Qlo, Khi, Klo,
                                             Vf);
  flash_kernel<<<1024, 512, 0, stream>>>(Qhi, Qlo, Khi, Klo, Vf, out);
}

// Round 11
// 92.736 us; speedup vs baseline: 1.7742x; 1.0187x over previous
//
#include <hip/hip_runtime.h>
#include <hip/hip_bf16.h>

// AttentionMechanismVaswani: B=2, G=2048, D=128, H=8, K=V=16
constexpr int Gc = 2048, Dc = 128, Hc = 8, Kc = 16;
constexpr int NCT = 24;       // proj col-tiles (8 Q, 8 K, 8 V)
constexpr int NCH = 128;      // G/16 kv-chunks
constexpr int SPLIT = 8;      // kv-split factor == waves per flash block
constexpr int QPW = 2;        // q-tiles per wave
constexpr int CPS = NCH / SPLIT;  // 16 chunks per wave

typedef __attribute__((ext_vector_type(8))) short bf16x8;
typedef __attribute__((ext_vector_type(8))) unsigned short u16x8;
typedef __attribute__((ext_vector_type(4))) unsigned int u32x4;
typedef __attribute__((ext_vector_type(4))) float f32x4;

// f32 -> bf16 (RNE) raw bits; hi/lo split gives ~2^-17 relative precision.
static __device__ __forceinline__ unsigned short f2bf(float f) {
  unsigned int u = __float_as_uint(f);
  u += 0x7FFFu + ((u >> 16) & 1u);
  return (unsigned short)(u >> 16);
}
static __device__ __forceinline__ float bf2f(unsigned short s) {
  return __uint_as_float(((unsigned int)s) << 16);
}
// GUARANTEED single-instruction 2^x: v_exp_f32 (hardware transcendental).
// The __builtin_amdgcn_exp2f/#else exp2f path risked a ~15-inst OCML call —
// the prime suspect for flash's VALU invariance across r2..r10.
static __device__ __forceinline__ float fexp2(float x) {
  float r;
  asm("v_exp_f32 %0, %1" : "=v"(r) : "v"(x));
  return r;
}
// guaranteed single-instruction pack: D.lo = bf16(a), D.hi = bf16(b)
static __device__ __forceinline__ unsigned int pk_bf16(float a, float b) {
  unsigned int r;
  asm("v_cvt_pk_bf16_f32 %0, %1, %2" : "=v"(r) : "v"(a), "v"(b));
  return r;
}

// ---------------------------------------------------------------------------
// Fused projection GEMM: C[4096, 384] = h * [c*Wq | Wk | Wv], reading h and W
// as f32 and splitting to bf16 hi/lo in-register (hh*wh + hh*wl + hl*wh;
// lo*lo dropped, ~2^-18). One wave per 16x16 output tile, 6144 waves.
// Epilogues: Q,K -> hi/lo bf16 row-major [bh][g][16];
//            V   -> merged [vh|vl] PV A-fragment [bh][chunk][64][8].
// W_Q pre-scaled by 0.25*log2(e) so scores come out in log2 units.
// ---------------------------------------------------------------------------
__global__ __launch_bounds__(256) void proj_gemm_kernel(
    const float* __restrict__ h, const float* __restrict__ Wq,
    const float* __restrict__ Wk, const float* __restrict__ Wv,
    unsigned short* __restrict__ Qhi, unsigned short* __restrict__ Qlo,
    unsigned short* __restrict__ Khi, unsigned short* __restrict__ Klo,
    unsigned short* __restrict__ Vf) {
  const int widx = blockIdx.x * 4 + (threadIdx.x >> 6);  // 0..6143
  const int ct = widx % NCT;
  const int rt = widx / NCT;
  const int l = threadIdx.x & 63;
  const int lane15 = l & 15, g4 = l >> 4;
  const int row0 = rt * 16;
  const int mat = ct >> 3, hh = ct & 7;

  const float* W = (mat == 0 ? Wq : (mat == 1 ? Wk : Wv)) + hh * (Dc * Kc);
  const float scale = (mat == 0) ? 0.25f * 1.44269504088896f : 1.0f;
  const float* hp = h + (size_t)(row0 + lane15) * Dc + g4 * 8;

  f32x4 acc = {0.f, 0.f, 0.f, 0.f};
#pragma unroll
  for (int kc = 0; kc < 4; ++kc) {
    // A fragment: h rows, f32 -> hi/lo bf16 in-register
    const float4 v0 = *(const float4*)(hp + kc * 32);
    const float4 v1 = *(const float4*)(hp + kc * 32 + 4);
    const float av[8] = {v0.x, v0.y, v0.z, v0.w, v1.x, v1.y, v1.z, v1.w};
    bf16x8 ah, al;
#pragma unroll
    for (int i = 0; i < 8; ++i) {
      const unsigned short hb = f2bf(av[i]);
      ah[i] = (short)hb;
      al[i] = (short)f2bf(av[i] - bf2f(hb));
    }
    // B fragment: W[d][col], d = kc*32 + g4*8 + j, col = lane15
    bf16x8 bh, bl;
#pragma unroll
    for (int j = 0; j < 8; ++j) {
      const float w = W[(kc * 32 + g4 * 8 + j) * Kc + lane15] * scale;
      const unsigned short hb = f2bf(w);
      bh[j] = (short)hb;
      bl[j] = (short)f2bf(w - bf2f(hb));
    }
    acc = __builtin_amdgcn_mfma_f32_16x16x32_bf16(ah, bh, acc, 0, 0, 0);
    acc = __builtin_amdgcn_mfma_f32_16x16x32_bf16(ah, bl, acc, 0, 0, 0);
    acc = __builtin_amdgcn_mfma_f32_16x16x32_bf16(al, bh, acc, 0, 0, 0);
  }

  // C-layout: lane holds rows row0 + 4*g4 + i, col = lane15 (within tile ct)
  const int b = row0 >> 11;
  const int g0 = row0 & 2047;
  const int bhh = b * Hc + hh;
  if (mat <= 1) {
    unsigned short* dhi = (mat == 0) ? Qhi : Khi;
    unsigned short* dlo = (mat == 0) ? Qlo : Klo;
#pragma unroll
    for (int i = 0; i < 4; ++i) {
      const size_t off = ((size_t)bhh * Gc + g0 + g4 * 4 + i) * Kc + lane15;
      const unsigned short hb = f2bf(acc[i]);
      dhi[off] = hb;
      dlo[off] = f2bf(acc[i] - bf2f(hb));
    }
  } else {
    const int c = g0 >> 4;  // row-tile == one kv-chunk
    u16x8 fv;
#pragma unroll
    for (int i = 0; i < 4; ++i) {
      const unsigned short hb = f2bf(acc[i]);
      fv[i] = hb;                           // k-slots 0-3: V-hi
      fv[i + 4] = f2bf(acc[i] - bf2f(hb));  // k-slots 4-7: V-lo
    }
    *(u16x8*)(Vf + ((size_t)(bhh * NCH + c) * 64 + l) * 8) = fv;
  }
}

// ---------------------------------------------------------------------------
// Flash attention: 2 q-tiles per wave, 8-way KV split, fused combine.
// Block = 8 waves = the 8 splits of one q-tile pair; each K/V chunk load
// feeds both q-tiles. Partials merged through LDS; out written directly.
// S^T = mfma(K, Q), scores in log2 units: K A-frag rows are kv, lane groups
// 0,1 take Khi (k-slots 0-15), groups 2,3 take Klo (16-31); B-frag = Q^T
// hi then lo, chained C. Score C-layout [m=4*g4+i][q=lane15] feeds PV's
// B-operand directly. SHARED defer-max state (one run_max/thr/branch per
// chunk for both q-tiles). All exp2 via raw v_exp_f32.
// __launch_bounds__(512, 6): cap VGPR ~85 -> 3 blocks/CU (24 waves/CU).
// ---------------------------------------------------------------------------
__global__ __launch_bounds__(512, 6) void flash_kernel(
    const unsigned short* __restrict__ Qhi, const unsigned short* __restrict__ Qlo,
    const unsigned short* __restrict__ Khi, const unsigned short* __restrict__ Klo,
    const unsigned short* __restrict__ Vf, float* __restrict__ out) {
  __shared__ f32x4 lo_s[SPLIT][QPW][64];   // 16 KB
  __shared__ float lml[SPLIT][QPW][16][2]; // 2 KB

  const int qg = blockIdx.x;            // 0..1023 q-tile pairs
  const int split = threadIdx.x >> 6;   // 0..7
  const int bh = qg >> 6;               // 64 pairs per (b,h)
  const int qi0 = (qg & 63) * QPW;
  const int l = threadIdx.x & 63;
  const int lane15 = l & 15, g4 = l >> 4, dhalf = g4 & 1;

  // Q fragments (B-operand) for both q-tiles: direct bf16 hi/lo loads
  bf16x8 bqh[QPW], bql[QPW];
#pragma unroll
  for (int t = 0; t < QPW; ++t) {
    const size_t qoff =
        ((size_t)bh * Gc + (qi0 + t) * 16 + lane15) * Kc + 8 * dhalf;
    bqh[t] = *(const bf16x8*)(Qhi + qoff);
    bql[t] = *(const bf16x8*)(Qlo + qoff);
  }

  const unsigned short* kbase = (g4 >= 2 ? Klo : Khi) +
      (size_t)bh * Gc * Kc + lane15 * Kc + 8 * dhalf + (size_t)split * CPS * 256;
  const unsigned short* vbase =
      Vf + ((size_t)bh * NCH * 64 + l) * 8 + (size_t)split * CPS * 512;

  const f32x4 z = {0.f, 0.f, 0.f, 0.f};
  f32x4 o[QPW] = {z, z};
  float run_max = -1e30f, thr = -1e30f;
  float lsum[QPW] = {0.f, 0.f};

#pragma unroll 4
  for (int c = 0; c < CPS; ++c) {
    const bf16x8 ak = *(const bf16x8*)(kbase + (size_t)c * 256);
    const bf16x8 av = *(const bf16x8*)(vbase + (size_t)c * 512);

    // QK^T for both tiles first (independent MFMA chains), then one shared
    // defer-max decision.
    f32x4 s[QPW];
#pragma unroll
    for (int t = 0; t < QPW; ++t) {
      f32x4 tmp = __builtin_amdgcn_mfma_f32_16x16x32_bf16(ak, bql[t], z, 0, 0, 0);
      s[t] = __builtin_amdgcn_mfma_f32_16x16x32_bf16(ak, bqh[t], tmp, 0, 0, 0);
      // s[t][i] = S^T[m = c*16 + 4*g4 + i][q = lane15], log2 units
    }

    float cm = fmaxf(fmaxf(s[0][0], s[0][1]), fmaxf(s[0][2], s[0][3]));
    cm = fmaxf(cm, fmaxf(fmaxf(s[1][0], s[1][1]), fmaxf(s[1][2], s[1][3])));
    if (!__all((int)(cm <= thr))) {
      float fm = fmaxf(cm, __shfl_xor(cm, 16));
      fm = fmaxf(fm, __shfl_xor(fm, 32));
      const float nm = fmaxf(run_max, fm);
      const float corr = fexp2(run_max - nm);  // 1st iter: exp2(-huge)=0
#pragma unroll
      for (int t = 0; t < QPW; ++t) {
        o[t][0] *= corr; o[t][1] *= corr; o[t][2] *= corr; o[t][3] *= corr;
        lsum[t] *= corr;
      }
      run_max = nm;
      thr = nm + 11.5f;  // ~8 nats of defer-max headroom
    }

#pragma unroll
    for (int t = 0; t < QPW; ++t) {
      const float p0 = fexp2(s[t][0] - run_max);
      const float p1 = fexp2(s[t][1] - run_max);
      const float p2 = fexp2(s[t][2] - run_max);
      const float p3 = fexp2(s[t][3] - run_max);
      lsum[t] += (p0 + p1) + (p2 + p3);

      const unsigned int w01 = pk_bf16(p0, p1);
      const unsigned int w23 = pk_bf16(p2, p3);
      const u32x4 bpv = {w01, w23, w01, w23};
      const bf16x8 bp = __builtin_bit_cast(bf16x8, bpv);
      o[t] = __builtin_amdgcn_mfma_f32_16x16x32_bf16(av, bp, o[t], 0, 0, 0);
    }
  }

#pragma unroll
  for (int t = 0; t < QPW; ++t) {
    float ls = lsum[t];
    ls += __shfl_xor(ls, 16);
    ls += __shfl_xor(ls, 32);
    lo_s[split][t][l] = o[t];
    if (l < 16) {
      lml[split][t][l][0] = run_max;
      lml[split][t][l][1] = ls;
    }
  }
  __syncthreads();

  if (threadIdx.x < QPW * 64) {  // wave t merges q-tile qi0+t
    const int t = split;  // 0..QPW-1 here
    float m[SPLIT], lv[SPLIT];
#pragma unroll
    for (int s = 0; s < SPLIT; ++s) {
      m[s] = lml[s][t][lane15][0];
      lv[s] = lml[s][t][lane15][1];
    }
    float M = m[0];
#pragma unroll
    for (int s = 1; s < SPLIT; ++s) M = fmaxf(M, m[s]);
    f32x4 acc = {0.f, 0.f, 0.f, 0.f};
    float den = 0.f;
#pragma unroll
    for (int s = 0; s < SPLIT; ++s) {
      const float w = fexp2(m[s] - M);
      den += w * lv[s];
      const f32x4 po = lo_s[s][t][l];
      acc[0] += w * po[0]; acc[1] += w * po[1];
      acc[2] += w * po[2]; acc[3] += w * po[3];
    }
    const float inv = 1.0f / den;
    f32x4 res;
    res[0] = acc[0] * inv; res[1] = acc[1] * inv;
    res[2] = acc[2] * inv; res[3] = acc[3] * inv;
    *(f32x4*)(out + ((size_t)bh * Gc + (qi0 + t) * 16 + lane15) * Kc + 4 * g4) =
        res;
  }
}

extern "C" void kernel_launch(void* const* d_in, const int* in_sizes, int n_in,
                              void* d_out, int out_size, void* d_ws, size_t ws_size,
                              hipStream_t stream) {
  const float* h  = (const float*)d_in[0];
  const float* Wq = (const float*)d_in[1];
  const float* Wk = (const float*)d_in[2];
  const float* Wv = (const float*)d_in[3];
  float* out = (float*)d_out;

  char* ws = (char*)d_ws;
  unsigned short* Qhi = (unsigned short*)(ws);                // 1 MB
  unsigned short* Qlo = (unsigned short*)(ws + (1u << 20));   // 1 MB
  unsigned short* Khi = (unsigned short*)(ws + (2u << 20));   // 1 MB
  unsigned short* Klo = (unsigned short*)(ws + (3u << 20));   // 1 MB
  unsigned short* Vf  = (unsigned short*)(ws + (4u << 20));   // 2 MB

  proj_gemm_kernel<<<1536, 256, 0, stream>>>(h, Wq, Wk, Wv, Qhi, Qlo, Khi, Klo,
                                             Vf);
  flash_kernel<<<1024, 512, 0, stream>>>(Qhi, Qlo, Khi, Klo, Vf, out);
}